// Round 12
// baseline (5028.388 us; speedup 1.0000x reference)
//
#include <hip/hip_runtime.h>
#include <cmath>

#define BATCH 2
#define CIN 3
#define HH 96
#define WW 96
#define NSP (HH*WW)      // 9216
#define CHN 64
#define C8 8
#define NBLK 5

#define PW 98            // padded width/height (3x3 convs)
#define PN (PW*PW)       // 9604 padded spatial
#define GUARD 128        // guard rows (spatial) each side of FBI buffers
#define FBST ((PN + 2*GUARD)*128)  // shorts per batch in FBI (hi|lo interleaved)

#define PW2 104          // padded width for 9x9 conv_out input
#define PN2 (PW2*PW2)    // 10816

#define NRB (NSP/32)     // 288 row-blocks in attention

#define LOG2E 1.4426950408889634f
#define BOOST 100.0f     // exponent boost: p' = 2^(e-M+BOOST), overflow-safe

typedef __attribute__((ext_vector_type(8))) short bf16x8;
typedef __attribute__((ext_vector_type(4))) float f32x4;

static __device__ __forceinline__ short f2b(float f) {
    union { float f; unsigned u; } v; v.f = f;
    unsigned r = (v.u + 0x7FFFu + ((v.u >> 16) & 1u)) >> 16;
    return (short)r;
}
static __device__ __forceinline__ float b2f(short s) {
    union { unsigned u; float f; } v; v.u = ((unsigned)(unsigned short)s) << 16;
    return v.f;
}
static __device__ __forceinline__ void split2(float v, short& hi, short& lo) {
    hi = f2b(v);
    lo = f2b(v - b2f(hi));
}

// ---------------------------------------------------------------------------
// weight prep: rw[blk][co][ci][3][3] fp32 -> Whi/Wlo[conv][kyx][co][ci] bf16
__global__ __launch_bounds__(256) void k_prep_w(const float* __restrict__ rw1,
        const float* __restrict__ rw2, short* __restrict__ Whi,
        short* __restrict__ Wlo) {
    int idx = blockIdx.x * 256 + threadIdx.x;
    const int TOT = NBLK*2*9*CHN*CHN;
    if (idx >= TOT) return;
    int ci  = idx & 63;
    int co  = (idx >> 6) & 63;
    int kyx = (idx >> 12) % 9;
    int conv = idx / (9*CHN*CHN);
    int blk = conv >> 1, s = conv & 1;
    const float* src = s ? rw2 : rw1;
    float v = src[(((size_t)(blk*CHN + co))*CHN + ci)*9 + kyx];
    short h, l; split2(v, h, l);
    Whi[idx] = h; Wlo[idx] = l;
}

// qkv weight prep: -> Wq[co=0..79][ci] bf16 hi/lo (0-7 wq, 8-15 wk, 16-79 wv)
__global__ __launch_bounds__(256) void k_prep_wqkv(const float* __restrict__ wq,
        const float* __restrict__ wk, const float* __restrict__ wv,
        short* __restrict__ Wh, short* __restrict__ Wl) {
    int idx = blockIdx.x * 256 + threadIdx.x;
    if (idx >= 80*CHN) return;
    int ci = idx & 63, co = idx >> 6;
    float v;
    if (co < 8)       v = wq[co*CHN + ci];
    else if (co < 16) v = wk[(co-8)*CHN + ci];
    else              v = wv[(co-16)*CHN + ci];
    short h, l; split2(v, h, l);
    Wh[idx] = h; Wl[idx] = l;
}

// conv_out weight prep: w_out[co][ci][81] fp32 -> Wo[kyx][co][ci] fp32
__global__ __launch_bounds__(256) void k_prep_wout(const float* __restrict__ w_out,
        float* __restrict__ Wo) {
    int idx = blockIdx.x * 256 + threadIdx.x;
    if (idx >= 81*CIN*CHN) return;
    int ci = idx & 63;
    int co = (idx >> 6) % 3;
    int kyx = idx / 192;
    Wo[idx] = w_out[((size_t)(co*CHN + ci))*81 + kyx];
}

// conv_in weight prep: w_in[co][ci][81] fp32 -> Win[k=ci*81+kyx][co] fp32
__global__ __launch_bounds__(256) void k_prep_win(const float* __restrict__ w_in,
        float* __restrict__ Win) {
    int idx = blockIdx.x * 256 + threadIdx.x;
    if (idx >= 243*CHN) return;
    int co = idx & 63;
    int k  = idx >> 6;          // 0..242
    int ci = k / 81, kk = k % 81;
    Win[idx] = w_in[((size_t)(co*CIN + ci))*81 + kk];
}

// ---------------------------------------------------------------------------
// conv 9x9 (3 -> 64), pad 4, + PReLU, two-phase (rolled ci/ky loops).
__global__ __launch_bounds__(256) void k_conv_in(const float* __restrict__ x,
        const float* __restrict__ Win, const float* __restrict__ bias,
        const float* __restrict__ a, float* __restrict__ FR,
        short* __restrict__ FBI) {
    __shared__ float Ls[32][65];
    int t = threadIdx.x;
    int blk = blockIdx.x;            // b*288 + y*3 + xc
    int b  = blk / 288;
    int y  = (blk % 288) / 3;
    int xc = blk % 3;
    int x0 = xc*32;
    int px  = t & 31;
    int cog = t >> 5;                // co group: co = cog*8 + r
    int xx = x0 + px;

    float acc[8];
    #pragma unroll
    for (int r = 0; r < 8; ++r) acc[r] = bias[cog*8 + r];

    #pragma unroll 1
    for (int ci = 0; ci < CIN; ++ci) {
        const float* xin = x + ((size_t)(b*CIN + ci))*NSP;
        #pragma unroll 1
        for (int ky = 0; ky < 9; ++ky) {
            int yy = y + ky - 4;
            bool vy = (yy >= 0 && yy < 96);
            float xv[9];
            #pragma unroll
            for (int kx = 0; kx < 9; ++kx) {
                int xs = xx - 4 + kx;
                xv[kx] = (vy && xs >= 0 && xs < 96) ? xin[yy*96 + xs] : 0.f;
            }
            const float* wrow = Win + (size_t)(ci*81 + ky*9)*64 + cog*8;
            #pragma unroll
            for (int kx = 0; kx < 9; ++kx) {
                float4 w0 = *(const float4*)(wrow + kx*64);
                float4 w1 = *(const float4*)(wrow + kx*64 + 4);
                float xvk = xv[kx];
                acc[0] = fmaf(xvk, w0.x, acc[0]);
                acc[1] = fmaf(xvk, w0.y, acc[1]);
                acc[2] = fmaf(xvk, w0.z, acc[2]);
                acc[3] = fmaf(xvk, w0.w, acc[3]);
                acc[4] = fmaf(xvk, w1.x, acc[4]);
                acc[5] = fmaf(xvk, w1.y, acc[5]);
                acc[6] = fmaf(xvk, w1.z, acc[6]);
                acc[7] = fmaf(xvk, w1.w, acc[7]);
            }
        }
    }
    float sl = a[0];
    #pragma unroll
    for (int r = 0; r < 8; ++r) {
        float v = acc[r];
        Ls[px][cog*8 + r] = v >= 0.f ? v : sl*v;
    }
    __syncthreads();

    int p = t >> 3, coq = (t & 7)*8;
    int np = (y + 1)*PW + x0 + p + 1;
    float v[8];
    #pragma unroll
    for (int u = 0; u < 8; ++u) v[u] = Ls[p][coq + u];
    float* fr = FR + ((size_t)b*PN + np)*CHN + coq;
    *(float4*)fr       = make_float4(v[0], v[1], v[2], v[3]);
    *(float4*)(fr + 4) = make_float4(v[4], v[5], v[6], v[7]);
    union { short s[8]; bf16x8 v8; } hu, lu;
    #pragma unroll
    for (int u = 0; u < 8; ++u) split2(v[u], hu.s[u], lu.s[u]);
    short* fo = FBI + (size_t)b*FBST + (size_t)np*128;
    *(bf16x8*)(fo + coq)      = hu.v8;
    *(bf16x8*)(fo + 64 + coq) = lu.v8;
}

// ---------------------------------------------------------------------------
// 3x3 conv 64->64, implicit GEMM, split-bf16 3-MFMA, 1-tap register prefetch.
// Wave = 16 sp x 16 co, block = 16 sp x 64 co, grid = B*588.
// Next tap's 8 fragments (act hi/lo + weight hi/lo, 2 cih) load while the
// current tap's 6 MFMA run -> load latency overlapped instead of serialized.
__global__ __launch_bounds__(256, 4) void k_conv3_mfma(
        const short* __restrict__ FBin,
        const short* __restrict__ Whi, const short* __restrict__ Wlo,
        const float* __restrict__ bias, const float* __restrict__ slope_p,
        float* __restrict__ FR, short* __restrict__ FBout, int mode) {
    int t = threadIdx.x;
    int w = t >> 6, lane = t & 63;
    int q = lane >> 4, n16 = lane & 15;
    int blk = blockIdx.x;
    int b = blk / 588, chunk = blk % 588;
    int nb = 98 + chunk*16 + n16;
    int ct = w;                          // this wave's co tile

    const short* fb = FBin + (size_t)b*FBST;
    int nbase = nb*128;
    int aw = (ct*16 + n16)*CHN + q*8;    // weight row offset (cih via +32)

    bf16x8 bh[2][2], bl[2][2], ah[2][2], al[2][2];
    // prefetch tap 0
    {
        int boff = nbase + (-PW - 1)*128;
        #pragma unroll
        for (int cih = 0; cih < 2; ++cih) {
            bh[0][cih] = *(const bf16x8*)(fb + boff + cih*32 + q*8);
            bl[0][cih] = *(const bf16x8*)(fb + boff + 64 + cih*32 + q*8);
            ah[0][cih] = *(const bf16x8*)(Whi + aw + cih*32);
            al[0][cih] = *(const bf16x8*)(Wlo + aw + cih*32);
        }
    }

    f32x4 acc = {0,0,0,0};
    #pragma unroll
    for (int kyx = 0; kyx < 9; ++kyx) {
        int cur = kyx & 1, nxt = cur ^ 1;
        if (kyx < 8) {
            int k2 = kyx + 1;
            int dy = k2/3 - 1, dx = k2%3 - 1;
            int boff = nbase + (dy*PW + dx)*128;
            const short* wph = Whi + (size_t)k2*CHN*CHN + aw;
            const short* wpl = Wlo + (size_t)k2*CHN*CHN + aw;
            #pragma unroll
            for (int cih = 0; cih < 2; ++cih) {
                bh[nxt][cih] = *(const bf16x8*)(fb + boff + cih*32 + q*8);
                bl[nxt][cih] = *(const bf16x8*)(fb + boff + 64 + cih*32 + q*8);
                ah[nxt][cih] = *(const bf16x8*)(wph + cih*32);
                al[nxt][cih] = *(const bf16x8*)(wpl + cih*32);
            }
        }
        #pragma unroll
        for (int cih = 0; cih < 2; ++cih) {
            acc = __builtin_amdgcn_mfma_f32_16x16x32_bf16(ah[cur][cih], bh[cur][cih], acc, 0, 0, 0);
            acc = __builtin_amdgcn_mfma_f32_16x16x32_bf16(ah[cur][cih], bl[cur][cih], acc, 0, 0, 0);
            acc = __builtin_amdgcn_mfma_f32_16x16x32_bf16(al[cur][cih], bh[cur][cih], acc, 0, 0, 0);
        }
    }

    int yy = nb / PW;
    int xx = nb - yy*PW;
    if (xx < 1 || xx > 96 || yy < 1 || yy > 96) return;
    float sl = slope_p[0];
    short* fbo = FBout + (size_t)b*FBST + (size_t)nb*128;
    float* fr  = FR + ((size_t)b*PN + nb)*CHN;
    #pragma unroll
    for (int r = 0; r < 4; ++r) {
        int co = ct*16 + q*4 + r;
        float v = acc[r] + bias[co];
        if (mode == 0) {
            v = v >= 0.f ? v : sl*v;
        } else {
            v += fr[co];
            fr[co] = v;
        }
        short h, l; split2(v, h, l);
        fbo[co]      = h;
        fbo[64 + co] = l;
    }
}

// ---------------------------------------------------------------------------
// qkv projection as 1x1-conv implicit GEMM (80 outputs = 8 q + 8 k + 64 v).
__global__ __launch_bounds__(256) void k_qkv_mfma(
        const short* __restrict__ FBin,
        const short* __restrict__ Wh, const short* __restrict__ Wl,
        const float* __restrict__ bq, const float* __restrict__ bk,
        const float* __restrict__ bv,
        short* __restrict__ Qb, short* __restrict__ Kb, short* __restrict__ Vb,
        float* __restrict__ Kinf) {
    int t = threadIdx.x;
    int w = t >> 6, lane = t & 63;
    int q = lane >> 4, n16 = lane & 15;
    int blk = blockIdx.x;
    int b = blk / 147, chunk = blk % 147;
    int nb = 98 + chunk*64 + w*16 + n16;

    const short* fb = FBin + (size_t)b*FBST;
    f32x4 acc[5] = {{0,0,0,0},{0,0,0,0},{0,0,0,0},{0,0,0,0},{0,0,0,0}};

    int nbase = nb*128;
    #pragma unroll
    for (int cih = 0; cih < 2; ++cih) {
        bf16x8 bhi = *(const bf16x8*)(fb + nbase + cih*32 + q*8);
        bf16x8 blo = *(const bf16x8*)(fb + nbase + 64 + cih*32 + q*8);
        #pragma unroll
        for (int ct = 0; ct < 5; ++ct) {
            int aoff = (ct*16 + n16)*CHN + cih*32 + q*8;
            bf16x8 ahi = *(const bf16x8*)(Wh + aoff);
            bf16x8 alo = *(const bf16x8*)(Wl + aoff);
            acc[ct] = __builtin_amdgcn_mfma_f32_16x16x32_bf16(ahi, bhi, acc[ct], 0, 0, 0);
            acc[ct] = __builtin_amdgcn_mfma_f32_16x16x32_bf16(ahi, blo, acc[ct], 0, 0, 0);
            acc[ct] = __builtin_amdgcn_mfma_f32_16x16x32_bf16(alo, bhi, acc[ct], 0, 0, 0);
        }
    }

    int yy = nb / PW;
    int xx = nb - yy*PW;
    float kabs[4] = {0.f, 0.f, 0.f, 0.f};
    if (xx >= 1 && xx <= 96 && yy >= 1 && yy <= 96) {
        int n = (yy - 1)*WW + (xx - 1);
        #pragma unroll
        for (int ct = 0; ct < 5; ++ct) {
            #pragma unroll
            for (int r = 0; r < 4; ++r) {
                int co = ct*16 + q*4 + r;
                float v = acc[ct][r];
                if (co < 8)
                    Qb[((size_t)b*NSP + n)*8 + co] = f2b((v + bq[co]) * LOG2E);
                else if (co < 16) {
                    float kv = v + bk[co-8];
                    kabs[r] = fabsf(kv) * 1.01f;
                    Kb[((size_t)b*NSP + n)*8 + (co-8)] = f2b(kv);
                } else
                    Vb[((size_t)(b*CHN + co-16))*NSP + n] = f2b(v + bv[co-16]);
            }
        }
    }
    #pragma unroll
    for (int r = 0; r < 4; ++r) {
        #pragma unroll
        for (int off = 1; off < 16; off <<= 1)
            kabs[r] = fmaxf(kabs[r], __shfl_xor(kabs[r], off));
    }
    if (q >= 2 && n16 == 0) {
        #pragma unroll
        for (int r = 0; r < 4; ++r)
            atomicMax((int*)&Kinf[(q - 2)*4 + r], __float_as_int(kabs[r]));
    }
}

// ---------------------------------------------------------------------------
// MFMA flash attention, bound-based softmax, j-split across 2 blocks,
// register double-buffered K/V prefetch (next chunk loads overlap compute).
__global__ __launch_bounds__(256) void k_attn_mfma(
        const short* __restrict__ Qb, const short* __restrict__ Kb,
        const short* __restrict__ Vb, const float* __restrict__ Kinf_p,
        float* __restrict__ Opg, float* __restrict__ lg) {
    __shared__ float Opart[4][2][16][68];
    __shared__ float lsh[4][2][16];

    int blk = blockIdx.x;
    int b    = blk / (NRB*2);
    int rb   = (blk % (NRB*2)) >> 1;
    int half = blk & 1;
    int i0 = rb*32;
    int t = threadIdx.x;
    int w = t >> 6;
    int lane = t & 63;
    int quad = lane >> 4, n16 = lane & 15;

    const short* Qp = Qb + ((size_t)b*NSP)*8;
    const short* Kp = Kb + ((size_t)b*NSP)*8;
    const short* Vp = Vb + ((size_t)b*CHN)*NSP;

    bf16x8 qf[2];
    float Mi[2];
    #pragma unroll
    for (int rg = 0; rg < 2; ++rg) {
        bf16x8 z = {0,0,0,0,0,0,0,0};
        qf[rg] = z;
        if (quad == 0)
            qf[rg] = *(const bf16x8*)(Qp + (size_t)(i0 + rg*16 + n16)*8);
        float s1 = 0.f;
        #pragma unroll
        for (int c = 0; c < 8; ++c)
            s1 += fabsf(b2f(qf[rg][c])) * Kinf_p[c];
        float Mv = s1 + 1.0f - BOOST;
        Mi[rg] = __shfl(Mv, n16);
    }

    f32x4 accO[2][4] = {{{0,0,0,0},{0,0,0,0},{0,0,0,0},{0,0,0,0}},
                        {{0,0,0,0},{0,0,0,0},{0,0,0,0},{0,0,0,0}}};
    float lp[2] = {0.f, 0.f};
    f32x4 ci[2];
    #pragma unroll
    for (int rg = 0; rg < 2; ++rg) {
        ci[rg][0] = -Mi[rg]; ci[rg][1] = -Mi[rg];
        ci[rg][2] = -Mi[rg]; ci[rg][3] = -Mi[rg];
    }

    // permuted kf row offset: j = (tt>>1)*32 + (n16>>2)*8 + (tt&1)*4 + (n16&3)
    int krow_base = (n16 >> 2)*8 + (n16 & 3);
    int jbase = half*4608 + w*1152;

    bf16x8 kfb[2][4];
    bf16x8 vfb[2][8];

    // prefetch chunk 0
    {
        int j0 = jbase;
        #pragma unroll
        for (int tt = 0; tt < 4; ++tt) {
            bf16x8 z = {0,0,0,0,0,0,0,0};
            kfb[0][tt] = z;
            if (quad == 0) {
                int jrow = j0 + (tt >> 1)*32 + (tt & 1)*4 + krow_base;
                kfb[0][tt] = *(const bf16x8*)(Kp + (size_t)jrow*8);
            }
        }
        #pragma unroll
        for (int ks = 0; ks < 2; ++ks)
            #pragma unroll
            for (int ct = 0; ct < 4; ++ct)
                vfb[0][ks*4 + ct] = *(const bf16x8*)(Vp + (size_t)(ct*16 + n16)*NSP
                                                     + j0 + ks*32 + quad*8);
    }

    for (int jc = 0; jc < 18; ++jc) {
        int cur = jc & 1, nxt = cur ^ 1;
        if (jc < 17) {
            int j0 = jbase + (jc + 1)*64;
            #pragma unroll
            for (int tt = 0; tt < 4; ++tt) {
                bf16x8 z = {0,0,0,0,0,0,0,0};
                kfb[nxt][tt] = z;
                if (quad == 0) {
                    int jrow = j0 + (tt >> 1)*32 + (tt & 1)*4 + krow_base;
                    kfb[nxt][tt] = *(const bf16x8*)(Kp + (size_t)jrow*8);
                }
            }
            #pragma unroll
            for (int ks = 0; ks < 2; ++ks)
                #pragma unroll
                for (int ct = 0; ct < 4; ++ct)
                    vfb[nxt][ks*4 + ct] = *(const bf16x8*)(Vp + (size_t)(ct*16 + n16)*NSP
                                                           + j0 + ks*32 + quad*8);
        }
        f32x4 e[2][4];
        #pragma unroll
        for (int rg = 0; rg < 2; ++rg)
            #pragma unroll
            for (int tt = 0; tt < 4; ++tt)
                e[rg][tt] = __builtin_amdgcn_mfma_f32_16x16x32_bf16(kfb[cur][tt], qf[rg], ci[rg], 0, 0, 0);
        #pragma unroll
        for (int rg = 0; rg < 2; ++rg) {
            float s = 0.f;
            #pragma unroll
            for (int tt = 0; tt < 4; ++tt)
                #pragma unroll
                for (int r = 0; r < 4; ++r) {
                    float p = exp2f(e[rg][tt][r]);
                    e[rg][tt][r] = p;
                    s += p;
                }
            lp[rg] += s;
        }
        #pragma unroll
        for (int ks = 0; ks < 2; ++ks) {
            #pragma unroll
            for (int rg = 0; rg < 2; ++rg) {
                union { int di[4]; bf16x8 v8; } pu;
                int t2 = ks*2;
                pu.di[0] = __builtin_amdgcn_perm(__float_as_uint(e[rg][t2][1]),
                                                 __float_as_uint(e[rg][t2][0]), 0x07060302u);
                pu.di[1] = __builtin_amdgcn_perm(__float_as_uint(e[rg][t2][3]),
                                                 __float_as_uint(e[rg][t2][2]), 0x07060302u);
                pu.di[2] = __builtin_amdgcn_perm(__float_as_uint(e[rg][t2+1][1]),
                                                 __float_as_uint(e[rg][t2+1][0]), 0x07060302u);
                pu.di[3] = __builtin_amdgcn_perm(__float_as_uint(e[rg][t2+1][3]),
                                                 __float_as_uint(e[rg][t2+1][2]), 0x07060302u);
                #pragma unroll
                for (int ct = 0; ct < 4; ++ct)
                    accO[rg][ct] = __builtin_amdgcn_mfma_f32_16x16x32_bf16(
                        pu.v8, vfb[cur][ks*4 + ct], accO[rg][ct], 0, 0, 0);
            }
        }
    }

    #pragma unroll
    for (int rg = 0; rg < 2; ++rg) {
        float l = lp[rg];
        l += __shfl_xor(l, 16);
        l += __shfl_xor(l, 32);
        if (quad == 0) lsh[w][rg][n16] = l;
        #pragma unroll
        for (int ct = 0; ct < 4; ++ct)
            #pragma unroll
            for (int r = 0; r < 4; ++r)
                Opart[w][rg][quad*4 + r][ct*16 + n16] = accO[rg][ct][r];
    }
    __syncthreads();

    int row = t >> 3;            // 0..31
    int rg = row >> 4, ii = row & 15;
    int c0 = (t & 7)*8;
    size_t obase = (((size_t)(b*NRB + rb))*2 + half)*2048 + (size_t)row*64;
    #pragma unroll
    for (int cc = 0; cc < 8; ++cc) {
        int c = c0 + cc;
        Opg[obase + c] = Opart[0][rg][ii][c] + Opart[1][rg][ii][c]
                       + Opart[2][rg][ii][c] + Opart[3][rg][ii][c];
    }
    if ((t & 7) == 0)
        lg[(((size_t)(b*NRB + rb))*2 + half)*32 + row] =
            lsh[0][rg][ii] + lsh[1][rg][ii] + lsh[2][rg][ii] + lsh[3][rg][ii];
}

// ---------------------------------------------------------------------------
// attention finalize: merge 2 j-halves, normalize, add residual, write AT.
__global__ __launch_bounds__(256) void k_attn_fin(
        const float* __restrict__ Opg, const float* __restrict__ lg,
        const float* __restrict__ FR, const float* __restrict__ gamma_p,
        float* __restrict__ AT) {
    int blk = blockIdx.x;            // b*NRB + rb
    int b = blk / NRB, rb = blk % NRB;
    int t = threadIdx.x;
    int row = t >> 3;
    int c0 = (t & 7)*8;
    float g = gamma_p[0];
    size_t ob = ((size_t)blk*2)*2048 + (size_t)row*64;
    float l0 = lg[((size_t)blk*2)*32 + row];
    float l1 = lg[((size_t)blk*2 + 1)*32 + row];
    float inv = g / fmaxf(l0 + l1, 1e-35f);
    int gi = rb*32 + row;
    int iy = gi / WW, ix = gi - iy*WW;
    size_t frb = ((size_t)b*PN + (iy + 1)*PW + ix + 1)*CHN;
    size_t atb = ((size_t)b*PN2 + (iy + 4)*PW2 + ix + 4)*CHN;
    #pragma unroll
    for (int cc = 0; cc < 8; ++cc) {
        int c = c0 + cc;
        float Ov = Opg[ob + c] + Opg[ob + 2048 + c];
        AT[atb + c] = Ov*inv + FR[frb + c];
    }
}

// ---------------------------------------------------------------------------
// conv 9x9 (64 -> 3) + tanh. Wave per 4 pixels, lane = ci.
__global__ __launch_bounds__(256) void k_conv_out(const float* __restrict__ AT,
        const float* __restrict__ Wo, const float* __restrict__ bias,
        float* __restrict__ out) {
    int t = threadIdx.x;
    int w = t >> 6, lane = t & 63;
    int base = blockIdx.x*16 + w*4;
    int b = base / NSP;
    int n0 = base % NSP;
    int y0 = n0 / WW, x0 = n0 % WW;

    float s[4][3] = {{0,0,0},{0,0,0},{0,0,0},{0,0,0}};
    for (int ky = 0; ky < 9; ++ky) {
        const float* arow = AT + ((size_t)b*PN2 + (size_t)(y0 + ky)*PW2 + x0)*CHN + lane;
        const float* wrow = Wo + (size_t)ky*9*192;
        float xv[12];
        #pragma unroll
        for (int u = 0; u < 12; ++u)
            xv[u] = arow[(size_t)u*CHN];
        #pragma unroll
        for (int kx = 0; kx < 9; ++kx) {
            float w0 = wrow[kx*192 +   0 + lane];
            float w1 = wrow[kx*192 +  64 + lane];
            float w2 = wrow[kx*192 + 128 + lane];
            #pragma unroll
            for (int p = 0; p < 4; ++p) {
                float x = xv[kx + p];
                s[p][0] = fmaf(x, w0, s[p][0]);
                s[p][1] = fmaf(x, w1, s[p][1]);
                s[p][2] = fmaf(x, w2, s[p][2]);
            }
        }
    }
    #pragma unroll
    for (int p = 0; p < 4; ++p)
        #pragma unroll
        for (int c = 0; c < 3; ++c) {
            float v = s[p][c];
            v += __shfl_xor(v, 1);
            v += __shfl_xor(v, 2);
            v += __shfl_xor(v, 4);
            v += __shfl_xor(v, 8);
            v += __shfl_xor(v, 16);
            v += __shfl_xor(v, 32);
            s[p][c] = v;
        }
    #pragma unroll
    for (int p = 0; p < 4; ++p)
        #pragma unroll
        for (int c = 0; c < 3; ++c)
            if (lane == p*3 + c)
                out[((size_t)(b*3 + c))*NSP + n0 + p] = tanhf(s[p][c] + bias[c]);
}

// ---------------------------------------------------------------------------
extern "C" void kernel_launch(void* const* d_in, const int* in_sizes, int n_in,
                              void* d_out, int out_size, void* d_ws, size_t ws_size,
                              hipStream_t stream) {
    (void)in_sizes; (void)n_in; (void)out_size; (void)ws_size;
    const float* x     = (const float*)d_in[0];
    const float* w_in  = (const float*)d_in[1];
    const float* b_in  = (const float*)d_in[2];
    const float* a_in  = (const float*)d_in[3];
    const float* rw1   = (const float*)d_in[4];
    const float* rb1   = (const float*)d_in[5];
    const float* ra    = (const float*)d_in[6];
    const float* rw2   = (const float*)d_in[7];
    const float* rb2   = (const float*)d_in[8];
    const float* wq    = (const float*)d_in[9];
    const float* bq    = (const float*)d_in[10];
    const float* wk    = (const float*)d_in[11];
    const float* bk    = (const float*)d_in[12];
    const float* wv    = (const float*)d_in[13];
    const float* bv    = (const float*)d_in[14];
    const float* gamma = (const float*)d_in[15];
    const float* w_out = (const float*)d_in[16];
    const float* b_out = (const float*)d_in[17];

    const size_t SZ_FR  = (size_t)BATCH*PN*CHN*4;        // 4,917,248
    const size_t SZ_FBI = (size_t)BATCH*FBST*2;          // 5,048,320
    const size_t SZ_WT  = (size_t)NBLK*2*9*CHN*CHN*2;    //   737,280
    const size_t SZ_QK  = (size_t)BATCH*NSP*C8*2;        //   294,912
    const size_t SZ_VB  = (size_t)BATCH*CHN*NSP*2;       // 2,359,296
    const size_t SZ_AT  = (size_t)BATCH*PN2*CHN*4;       // 5,537,792
    const size_t SZ_WO  = (size_t)81*CIN*CHN*4;          //    62,208
    const size_t SZ_WIN = (size_t)243*CHN*4;             //    62,208
    const size_t SZ_WQ  = (size_t)80*CHN*2;              //    10,240
    const size_t SZ_OP  = (size_t)BATCH*NRB*2*32*64*4;   // 18,874,368
    const size_t SZ_LG  = (size_t)BATCH*NRB*2*32*4;      //   147,456
    char* p = (char*)d_ws;
    float* FR      = (float*)p;           p += SZ_FR;
    short* FBI0raw = (short*)p;           p += SZ_FBI;
    short* FBI1raw = (short*)p;           p += SZ_FBI;
    short* Whi     = (short*)p;           p += SZ_WT;
    short* Wlo     = (short*)p;           p += SZ_WT;
    short* Qb16    = (short*)p;           p += SZ_QK;
    short* Kb16    = (short*)p;           p += SZ_QK;
    short* Vb16    = (short*)p;           p += SZ_VB;
    float* AT      = (float*)p;           p += SZ_AT;
    float* Wo      = (float*)p;           p += SZ_WO;
    float* Win     = (float*)p;           p += SZ_WIN;
    short* Wqh     = (short*)p;           p += SZ_WQ;
    short* Wql     = (short*)p;           p += SZ_WQ;
    float* Opg     = (float*)p;           p += SZ_OP;
    float* lgb     = (float*)p;           p += SZ_LG;
    float* Kinf    = (float*)p;           p += 32;
    short* FBI0 = FBI0raw + (size_t)GUARD*128;
    short* FBI1 = FBI1raw + (size_t)GUARD*128;
    float* outp = (float*)d_out;

    hipMemsetAsync(FR, 0, SZ_FR, stream);
    hipMemsetAsync(FBI0raw, 0, SZ_FBI, stream);
    hipMemsetAsync(FBI1raw, 0, SZ_FBI, stream);
    hipMemsetAsync(AT, 0, SZ_AT, stream);
    hipMemsetAsync(Kinf, 0, 32, stream);

    dim3 blk(256);

    k_prep_w<<<(NBLK*2*9*CHN*CHN + 255)/256, blk, 0, stream>>>(rw1, rw2, Whi, Wlo);
    k_prep_wqkv<<<(80*CHN + 255)/256, blk, 0, stream>>>(wq, wk, wv, Wqh, Wql);
    k_prep_wout<<<(81*CIN*CHN + 255)/256, blk, 0, stream>>>(w_out, Wo);
    k_prep_win<<<(243*CHN + 255)/256, blk, 0, stream>>>(w_in, Win);
    k_conv_in<<<BATCH*96*3, blk, 0, stream>>>(x, Win, b_in, a_in, FR, FBI0);
    for (int i = 0; i < NBLK; ++i) {
        k_conv3_mfma<<<BATCH*588, blk, 0, stream>>>(
            FBI0,
            Whi + (size_t)(2*i)*9*CHN*CHN, Wlo + (size_t)(2*i)*9*CHN*CHN,
            rb1 + i*CHN, ra + i, (float*)nullptr, FBI1, 0);
        k_conv3_mfma<<<BATCH*588, blk, 0, stream>>>(
            FBI1,
            Whi + (size_t)(2*i+1)*9*CHN*CHN, Wlo + (size_t)(2*i+1)*9*CHN*CHN,
            rb2 + i*CHN, ra + i, FR, FBI0, 1);
    }
    k_qkv_mfma<<<BATCH*147, blk, 0, stream>>>(
        FBI0, Wqh, Wql, bq, bk, bv, Qb16, Kb16, Vb16, Kinf);
    k_attn_mfma<<<BATCH*NRB*2, blk, 0, stream>>>(
        Qb16, Kb16, Vb16, Kinf, Opg, lgb);
    k_attn_fin<<<BATCH*NRB, blk, 0, stream>>>(Opg, lgb, FR, gamma, AT);
    k_conv_out<<<(BATCH*NSP)/16, blk, 0, stream>>>(AT, Wo, b_out, outp);
}

// Round 13
// 805.567 us; speedup vs baseline: 6.2421x; 6.2421x over previous
//
#include <hip/hip_runtime.h>
#include <cmath>

#define BATCH 2
#define CIN 3
#define HH 96
#define WW 96
#define NSP (HH*WW)      // 9216
#define CHN 64
#define C8 8
#define NBLK 5

#define PW 98            // padded width/height (3x3 convs)
#define PN (PW*PW)       // 9604 padded spatial
#define GUARD 128        // guard rows (spatial) each side of FBI buffers
#define FBST ((PN + 2*GUARD)*128)  // shorts per batch in FBI (hi|lo interleaved)

#define PW2 104          // padded width for 9x9 conv_out input
#define PN2 (PW2*PW2)    // 10816

#define NRB (NSP/32)     // 288 row-blocks in attention

#define LOG2E 1.4426950408889634f
#define BOOST 100.0f     // exponent boost: p' = 2^(e-M+BOOST), overflow-safe

typedef __attribute__((ext_vector_type(8))) short bf16x8;
typedef __attribute__((ext_vector_type(4))) float f32x4;

static __device__ __forceinline__ short f2b(float f) {
    union { float f; unsigned u; } v; v.f = f;
    unsigned r = (v.u + 0x7FFFu + ((v.u >> 16) & 1u)) >> 16;
    return (short)r;
}
static __device__ __forceinline__ float b2f(short s) {
    union { unsigned u; float f; } v; v.u = ((unsigned)(unsigned short)s) << 16;
    return v.f;
}
static __device__ __forceinline__ void split2(float v, short& hi, short& lo) {
    hi = f2b(v);
    lo = f2b(v - b2f(hi));
}

// ---------------------------------------------------------------------------
// weight prep: rw[blk][co][ci][3][3] fp32 -> Whi/Wlo[conv][kyx][co][ci] bf16
__global__ __launch_bounds__(256) void k_prep_w(const float* __restrict__ rw1,
        const float* __restrict__ rw2, short* __restrict__ Whi,
        short* __restrict__ Wlo) {
    int idx = blockIdx.x * 256 + threadIdx.x;
    const int TOT = NBLK*2*9*CHN*CHN;
    if (idx >= TOT) return;
    int ci  = idx & 63;
    int co  = (idx >> 6) & 63;
    int kyx = (idx >> 12) % 9;
    int conv = idx / (9*CHN*CHN);
    int blk = conv >> 1, s = conv & 1;
    const float* src = s ? rw2 : rw1;
    float v = src[(((size_t)(blk*CHN + co))*CHN + ci)*9 + kyx];
    short h, l; split2(v, h, l);
    Whi[idx] = h; Wlo[idx] = l;
}

// qkv weight prep: -> Wq[co=0..79][ci] bf16 hi/lo (0-7 wq, 8-15 wk, 16-79 wv)
__global__ __launch_bounds__(256) void k_prep_wqkv(const float* __restrict__ wq,
        const float* __restrict__ wk, const float* __restrict__ wv,
        short* __restrict__ Wh, short* __restrict__ Wl) {
    int idx = blockIdx.x * 256 + threadIdx.x;
    if (idx >= 80*CHN) return;
    int ci = idx & 63, co = idx >> 6;
    float v;
    if (co < 8)       v = wq[co*CHN + ci];
    else if (co < 16) v = wk[(co-8)*CHN + ci];
    else              v = wv[(co-16)*CHN + ci];
    short h, l; split2(v, h, l);
    Wh[idx] = h; Wl[idx] = l;
}

// conv_out weight prep: w_out[co][ci][81] fp32 -> Wo[kyx][co][ci] fp32
__global__ __launch_bounds__(256) void k_prep_wout(const float* __restrict__ w_out,
        float* __restrict__ Wo) {
    int idx = blockIdx.x * 256 + threadIdx.x;
    if (idx >= 81*CIN*CHN) return;
    int ci = idx & 63;
    int co = (idx >> 6) % 3;
    int kyx = idx / 192;
    Wo[idx] = w_out[((size_t)(co*CHN + ci))*81 + kyx];
}

// conv_in weight prep: w_in[co][ci][81] fp32 -> Win[k=ci*81+kyx][co] fp32
__global__ __launch_bounds__(256) void k_prep_win(const float* __restrict__ w_in,
        float* __restrict__ Win) {
    int idx = blockIdx.x * 256 + threadIdx.x;
    if (idx >= 243*CHN) return;
    int co = idx & 63;
    int k  = idx >> 6;          // 0..242
    int ci = k / 81, kk = k % 81;
    Win[idx] = w_in[((size_t)(co*CIN + ci))*81 + kk];
}

// ---------------------------------------------------------------------------
// conv 9x9 (3 -> 64), pad 4, + PReLU, two-phase (rolled ci/ky loops).
__global__ __launch_bounds__(256) void k_conv_in(const float* __restrict__ x,
        const float* __restrict__ Win, const float* __restrict__ bias,
        const float* __restrict__ a, float* __restrict__ FR,
        short* __restrict__ FBI) {
    __shared__ float Ls[32][65];
    int t = threadIdx.x;
    int blk = blockIdx.x;            // b*288 + y*3 + xc
    int b  = blk / 288;
    int y  = (blk % 288) / 3;
    int xc = blk % 3;
    int x0 = xc*32;
    int px  = t & 31;
    int cog = t >> 5;                // co group: co = cog*8 + r
    int xx = x0 + px;

    float acc[8];
    #pragma unroll
    for (int r = 0; r < 8; ++r) acc[r] = bias[cog*8 + r];

    #pragma unroll 1
    for (int ci = 0; ci < CIN; ++ci) {
        const float* xin = x + ((size_t)(b*CIN + ci))*NSP;
        #pragma unroll 1
        for (int ky = 0; ky < 9; ++ky) {
            int yy = y + ky - 4;
            bool vy = (yy >= 0 && yy < 96);
            float xv[9];
            #pragma unroll
            for (int kx = 0; kx < 9; ++kx) {
                int xs = xx - 4 + kx;
                xv[kx] = (vy && xs >= 0 && xs < 96) ? xin[yy*96 + xs] : 0.f;
            }
            const float* wrow = Win + (size_t)(ci*81 + ky*9)*64 + cog*8;
            #pragma unroll
            for (int kx = 0; kx < 9; ++kx) {
                float4 w0 = *(const float4*)(wrow + kx*64);
                float4 w1 = *(const float4*)(wrow + kx*64 + 4);
                float xvk = xv[kx];
                acc[0] = fmaf(xvk, w0.x, acc[0]);
                acc[1] = fmaf(xvk, w0.y, acc[1]);
                acc[2] = fmaf(xvk, w0.z, acc[2]);
                acc[3] = fmaf(xvk, w0.w, acc[3]);
                acc[4] = fmaf(xvk, w1.x, acc[4]);
                acc[5] = fmaf(xvk, w1.y, acc[5]);
                acc[6] = fmaf(xvk, w1.z, acc[6]);
                acc[7] = fmaf(xvk, w1.w, acc[7]);
            }
        }
    }
    float sl = a[0];
    #pragma unroll
    for (int r = 0; r < 8; ++r) {
        float v = acc[r];
        Ls[px][cog*8 + r] = v >= 0.f ? v : sl*v;
    }
    __syncthreads();

    int p = t >> 3, coq = (t & 7)*8;
    int np = (y + 1)*PW + x0 + p + 1;
    float v[8];
    #pragma unroll
    for (int u = 0; u < 8; ++u) v[u] = Ls[p][coq + u];
    float* fr = FR + ((size_t)b*PN + np)*CHN + coq;
    *(float4*)fr       = make_float4(v[0], v[1], v[2], v[3]);
    *(float4*)(fr + 4) = make_float4(v[4], v[5], v[6], v[7]);
    union { short s[8]; bf16x8 v8; } hu, lu;
    #pragma unroll
    for (int u = 0; u < 8; ++u) split2(v[u], hu.s[u], lu.s[u]);
    short* fo = FBI + (size_t)b*FBST + (size_t)np*128;
    *(bf16x8*)(fo + coq)      = hu.v8;
    *(bf16x8*)(fo + 64 + coq) = lu.v8;
}

// ---------------------------------------------------------------------------
// 3x3 conv 64->64, implicit GEMM, split-bf16 3-MFMA, 1-tap register prefetch
// (kyx loop fully unrolled -> buffer indices compile-time -> stays in VGPRs).
__global__ __launch_bounds__(256, 4) void k_conv3_mfma(
        const short* __restrict__ FBin,
        const short* __restrict__ Whi, const short* __restrict__ Wlo,
        const float* __restrict__ bias, const float* __restrict__ slope_p,
        float* __restrict__ FR, short* __restrict__ FBout, int mode) {
    int t = threadIdx.x;
    int w = t >> 6, lane = t & 63;
    int q = lane >> 4, n16 = lane & 15;
    int blk = blockIdx.x;
    int b = blk / 588, chunk = blk % 588;
    int nb = 98 + chunk*16 + n16;
    int ct = w;                          // this wave's co tile

    const short* fb = FBin + (size_t)b*FBST;
    int nbase = nb*128;
    int aw = (ct*16 + n16)*CHN + q*8;    // weight row offset (cih via +32)

    bf16x8 bh[2][2], bl[2][2], ah[2][2], al[2][2];
    // prefetch tap 0
    {
        int boff = nbase + (-PW - 1)*128;
        #pragma unroll
        for (int cih = 0; cih < 2; ++cih) {
            bh[0][cih] = *(const bf16x8*)(fb + boff + cih*32 + q*8);
            bl[0][cih] = *(const bf16x8*)(fb + boff + 64 + cih*32 + q*8);
            ah[0][cih] = *(const bf16x8*)(Whi + aw + cih*32);
            al[0][cih] = *(const bf16x8*)(Wlo + aw + cih*32);
        }
    }

    f32x4 acc = {0,0,0,0};
    #pragma unroll
    for (int kyx = 0; kyx < 9; ++kyx) {
        int cur = kyx & 1, nxt = cur ^ 1;
        if (kyx < 8) {
            int k2 = kyx + 1;
            int dy = k2/3 - 1, dx = k2%3 - 1;
            int boff = nbase + (dy*PW + dx)*128;
            const short* wph = Whi + (size_t)k2*CHN*CHN + aw;
            const short* wpl = Wlo + (size_t)k2*CHN*CHN + aw;
            #pragma unroll
            for (int cih = 0; cih < 2; ++cih) {
                bh[nxt][cih] = *(const bf16x8*)(fb + boff + cih*32 + q*8);
                bl[nxt][cih] = *(const bf16x8*)(fb + boff + 64 + cih*32 + q*8);
                ah[nxt][cih] = *(const bf16x8*)(wph + cih*32);
                al[nxt][cih] = *(const bf16x8*)(wpl + cih*32);
            }
        }
        #pragma unroll
        for (int cih = 0; cih < 2; ++cih) {
            acc = __builtin_amdgcn_mfma_f32_16x16x32_bf16(ah[cur][cih], bh[cur][cih], acc, 0, 0, 0);
            acc = __builtin_amdgcn_mfma_f32_16x16x32_bf16(ah[cur][cih], bl[cur][cih], acc, 0, 0, 0);
            acc = __builtin_amdgcn_mfma_f32_16x16x32_bf16(al[cur][cih], bh[cur][cih], acc, 0, 0, 0);
        }
    }

    int yy = nb / PW;
    int xx = nb - yy*PW;
    if (xx < 1 || xx > 96 || yy < 1 || yy > 96) return;
    float sl = slope_p[0];
    short* fbo = FBout + (size_t)b*FBST + (size_t)nb*128;
    float* fr  = FR + ((size_t)b*PN + nb)*CHN;
    #pragma unroll
    for (int r = 0; r < 4; ++r) {
        int co = ct*16 + q*4 + r;
        float v = acc[r] + bias[co];
        if (mode == 0) {
            v = v >= 0.f ? v : sl*v;
        } else {
            v += fr[co];
            fr[co] = v;
        }
        short h, l; split2(v, h, l);
        fbo[co]      = h;
        fbo[64 + co] = l;
    }
}

// ---------------------------------------------------------------------------
// qkv projection as 1x1-conv implicit GEMM (80 outputs = 8 q + 8 k + 64 v).
__global__ __launch_bounds__(256) void k_qkv_mfma(
        const short* __restrict__ FBin,
        const short* __restrict__ Wh, const short* __restrict__ Wl,
        const float* __restrict__ bq, const float* __restrict__ bk,
        const float* __restrict__ bv,
        short* __restrict__ Qb, short* __restrict__ Kb, short* __restrict__ Vb,
        float* __restrict__ Kinf) {
    int t = threadIdx.x;
    int w = t >> 6, lane = t & 63;
    int q = lane >> 4, n16 = lane & 15;
    int blk = blockIdx.x;
    int b = blk / 147, chunk = blk % 147;
    int nb = 98 + chunk*64 + w*16 + n16;

    const short* fb = FBin + (size_t)b*FBST;
    f32x4 acc[5] = {{0,0,0,0},{0,0,0,0},{0,0,0,0},{0,0,0,0},{0,0,0,0}};

    int nbase = nb*128;
    #pragma unroll
    for (int cih = 0; cih < 2; ++cih) {
        bf16x8 bhi = *(const bf16x8*)(fb + nbase + cih*32 + q*8);
        bf16x8 blo = *(const bf16x8*)(fb + nbase + 64 + cih*32 + q*8);
        #pragma unroll
        for (int ct = 0; ct < 5; ++ct) {
            int aoff = (ct*16 + n16)*CHN + cih*32 + q*8;
            bf16x8 ahi = *(const bf16x8*)(Wh + aoff);
            bf16x8 alo = *(const bf16x8*)(Wl + aoff);
            acc[ct] = __builtin_amdgcn_mfma_f32_16x16x32_bf16(ahi, bhi, acc[ct], 0, 0, 0);
            acc[ct] = __builtin_amdgcn_mfma_f32_16x16x32_bf16(ahi, blo, acc[ct], 0, 0, 0);
            acc[ct] = __builtin_amdgcn_mfma_f32_16x16x32_bf16(alo, bhi, acc[ct], 0, 0, 0);
        }
    }

    int yy = nb / PW;
    int xx = nb - yy*PW;
    float kabs[4] = {0.f, 0.f, 0.f, 0.f};
    if (xx >= 1 && xx <= 96 && yy >= 1 && yy <= 96) {
        int n = (yy - 1)*WW + (xx - 1);
        #pragma unroll
        for (int ct = 0; ct < 5; ++ct) {
            #pragma unroll
            for (int r = 0; r < 4; ++r) {
                int co = ct*16 + q*4 + r;
                float v = acc[ct][r];
                if (co < 8)
                    Qb[((size_t)b*NSP + n)*8 + co] = f2b((v + bq[co]) * LOG2E);
                else if (co < 16) {
                    float kv = v + bk[co-8];
                    kabs[r] = fabsf(kv) * 1.01f;
                    Kb[((size_t)b*NSP + n)*8 + (co-8)] = f2b(kv);
                } else
                    Vb[((size_t)(b*CHN + co-16))*NSP + n] = f2b(v + bv[co-16]);
            }
        }
    }
    #pragma unroll
    for (int r = 0; r < 4; ++r) {
        #pragma unroll
        for (int off = 1; off < 16; off <<= 1)
            kabs[r] = fmaxf(kabs[r], __shfl_xor(kabs[r], off));
    }
    if (q >= 2 && n16 == 0) {
        #pragma unroll
        for (int r = 0; r < 4; ++r)
            atomicMax((int*)&Kinf[(q - 2)*4 + r], __float_as_int(kabs[r]));
    }
}

// ---------------------------------------------------------------------------
// chunk buffer for attention double-buffering: named structs + fully-inlined
// helpers keep every array index compile-time -> buffers stay in VGPRs
// (round-11's runtime `cur` index demoted them to scratch: 630 MB spill).
struct CB { bf16x8 kf[4]; bf16x8 vf[8]; };

static __device__ __forceinline__ void attn_load(CB& cb,
        const short* __restrict__ Kp, const short* __restrict__ Vp,
        int j0, int quad, int n16, int krow_base) {
    #pragma unroll
    for (int tt = 0; tt < 4; ++tt) {
        bf16x8 z = {0,0,0,0,0,0,0,0};
        cb.kf[tt] = z;
        if (quad == 0) {
            int jrow = j0 + (tt >> 1)*32 + (tt & 1)*4 + krow_base;
            cb.kf[tt] = *(const bf16x8*)(Kp + (size_t)jrow*8);
        }
    }
    #pragma unroll
    for (int ks = 0; ks < 2; ++ks)
        #pragma unroll
        for (int ct = 0; ct < 4; ++ct)
            cb.vf[ks*4 + ct] = *(const bf16x8*)(Vp + (size_t)(ct*16 + n16)*NSP
                                                + j0 + ks*32 + quad*8);
}

static __device__ __forceinline__ void attn_compute(const CB& cb,
        const bf16x8 (&qf)[2], const f32x4 (&ci)[2],
        f32x4 (&accO)[2][4], float (&lp)[2]) {
    f32x4 e[2][4];
    #pragma unroll
    for (int rg = 0; rg < 2; ++rg)
        #pragma unroll
        for (int tt = 0; tt < 4; ++tt)
            e[rg][tt] = __builtin_amdgcn_mfma_f32_16x16x32_bf16(cb.kf[tt], qf[rg], ci[rg], 0, 0, 0);
    #pragma unroll
    for (int rg = 0; rg < 2; ++rg) {
        float s = 0.f;
        #pragma unroll
        for (int tt = 0; tt < 4; ++tt)
            #pragma unroll
            for (int r = 0; r < 4; ++r) {
                float p = exp2f(e[rg][tt][r]);
                e[rg][tt][r] = p;
                s += p;
            }
        lp[rg] += s;
    }
    #pragma unroll
    for (int ks = 0; ks < 2; ++ks) {
        #pragma unroll
        for (int rg = 0; rg < 2; ++rg) {
            union { int di[4]; bf16x8 v8; } pu;
            int t2 = ks*2;
            pu.di[0] = __builtin_amdgcn_perm(__float_as_uint(e[rg][t2][1]),
                                             __float_as_uint(e[rg][t2][0]), 0x07060302u);
            pu.di[1] = __builtin_amdgcn_perm(__float_as_uint(e[rg][t2][3]),
                                             __float_as_uint(e[rg][t2][2]), 0x07060302u);
            pu.di[2] = __builtin_amdgcn_perm(__float_as_uint(e[rg][t2+1][1]),
                                             __float_as_uint(e[rg][t2+1][0]), 0x07060302u);
            pu.di[3] = __builtin_amdgcn_perm(__float_as_uint(e[rg][t2+1][3]),
                                             __float_as_uint(e[rg][t2+1][2]), 0x07060302u);
            #pragma unroll
            for (int ct = 0; ct < 4; ++ct)
                accO[rg][ct] = __builtin_amdgcn_mfma_f32_16x16x32_bf16(
                    pu.v8, cb.vf[ks*4 + ct], accO[rg][ct], 0, 0, 0);
        }
    }
}

// MFMA flash attention, bound-based softmax, j-split across 2 blocks,
// register double-buffered K/V prefetch with compile-time buffer selection.
__global__ __launch_bounds__(256) void k_attn_mfma(
        const short* __restrict__ Qb, const short* __restrict__ Kb,
        const short* __restrict__ Vb, const float* __restrict__ Kinf_p,
        float* __restrict__ Opg, float* __restrict__ lg) {
    __shared__ float Opart[4][2][16][68];
    __shared__ float lsh[4][2][16];

    int blk = blockIdx.x;
    int b    = blk / (NRB*2);
    int rb   = (blk % (NRB*2)) >> 1;
    int half = blk & 1;
    int i0 = rb*32;
    int t = threadIdx.x;
    int w = t >> 6;
    int lane = t & 63;
    int quad = lane >> 4, n16 = lane & 15;

    const short* Qp = Qb + ((size_t)b*NSP)*8;
    const short* Kp = Kb + ((size_t)b*NSP)*8;
    const short* Vp = Vb + ((size_t)b*CHN)*NSP;

    bf16x8 qf[2];
    float Mi[2];
    #pragma unroll
    for (int rg = 0; rg < 2; ++rg) {
        bf16x8 z = {0,0,0,0,0,0,0,0};
        qf[rg] = z;
        if (quad == 0)
            qf[rg] = *(const bf16x8*)(Qp + (size_t)(i0 + rg*16 + n16)*8);
        float s1 = 0.f;
        #pragma unroll
        for (int c = 0; c < 8; ++c)
            s1 += fabsf(b2f(qf[rg][c])) * Kinf_p[c];
        float Mv = s1 + 1.0f - BOOST;
        Mi[rg] = __shfl(Mv, n16);
    }

    f32x4 accO[2][4] = {{{0,0,0,0},{0,0,0,0},{0,0,0,0},{0,0,0,0}},
                        {{0,0,0,0},{0,0,0,0},{0,0,0,0},{0,0,0,0}}};
    float lp[2] = {0.f, 0.f};
    f32x4 ci[2];
    #pragma unroll
    for (int rg = 0; rg < 2; ++rg) {
        ci[rg][0] = -Mi[rg]; ci[rg][1] = -Mi[rg];
        ci[rg][2] = -Mi[rg]; ci[rg][3] = -Mi[rg];
    }

    // permuted kf row offset: j = (tt>>1)*32 + (n16>>2)*8 + (tt&1)*4 + (n16&3)
    int krow_base = (n16 >> 2)*8 + (n16 & 3);
    int jbase = half*4608 + w*1152;

    CB bufA, bufB;
    attn_load(bufA, Kp, Vp, jbase, quad, n16, krow_base);

    #pragma unroll 1
    for (int jc = 0; jc < 18; jc += 2) {
        attn_load(bufB, Kp, Vp, jbase + (jc + 1)*64, quad, n16, krow_base);
        attn_compute(bufA, qf, ci, accO, lp);
        if (jc + 2 < 18)
            attn_load(bufA, Kp, Vp, jbase + (jc + 2)*64, quad, n16, krow_base);
        attn_compute(bufB, qf, ci, accO, lp);
    }

    #pragma unroll
    for (int rg = 0; rg < 2; ++rg) {
        float l = lp[rg];
        l += __shfl_xor(l, 16);
        l += __shfl_xor(l, 32);
        if (quad == 0) lsh[w][rg][n16] = l;
        #pragma unroll
        for (int ct = 0; ct < 4; ++ct)
            #pragma unroll
            for (int r = 0; r < 4; ++r)
                Opart[w][rg][quad*4 + r][ct*16 + n16] = accO[rg][ct][r];
    }
    __syncthreads();

    int row = t >> 3;            // 0..31
    int rg = row >> 4, ii = row & 15;
    int c0 = (t & 7)*8;
    size_t obase = (((size_t)(b*NRB + rb))*2 + half)*2048 + (size_t)row*64;
    #pragma unroll
    for (int cc = 0; cc < 8; ++cc) {
        int c = c0 + cc;
        Opg[obase + c] = Opart[0][rg][ii][c] + Opart[1][rg][ii][c]
                       + Opart[2][rg][ii][c] + Opart[3][rg][ii][c];
    }
    if ((t & 7) == 0)
        lg[(((size_t)(b*NRB + rb))*2 + half)*32 + row] =
            lsh[0][rg][ii] + lsh[1][rg][ii] + lsh[2][rg][ii] + lsh[3][rg][ii];
}

// ---------------------------------------------------------------------------
// attention finalize: merge 2 j-halves, normalize, add residual, write AT.
__global__ __launch_bounds__(256) void k_attn_fin(
        const float* __restrict__ Opg, const float* __restrict__ lg,
        const float* __restrict__ FR, const float* __restrict__ gamma_p,
        float* __restrict__ AT) {
    int blk = blockIdx.x;            // b*NRB + rb
    int b = blk / NRB, rb = blk % NRB;
    int t = threadIdx.x;
    int row = t >> 3;
    int c0 = (t & 7)*8;
    float g = gamma_p[0];
    size_t ob = ((size_t)blk*2)*2048 + (size_t)row*64;
    float l0 = lg[((size_t)blk*2)*32 + row];
    float l1 = lg[((size_t)blk*2 + 1)*32 + row];
    float inv = g / fmaxf(l0 + l1, 1e-35f);
    int gi = rb*32 + row;
    int iy = gi / WW, ix = gi - iy*WW;
    size_t frb = ((size_t)b*PN + (iy + 1)*PW + ix + 1)*CHN;
    size_t atb = ((size_t)b*PN2 + (iy + 4)*PW2 + ix + 4)*CHN;
    #pragma unroll
    for (int cc = 0; cc < 8; ++cc) {
        int c = c0 + cc;
        float Ov = Opg[ob + c] + Opg[ob + 2048 + c];
        AT[atb + c] = Ov*inv + FR[frb + c];
    }
}

// ---------------------------------------------------------------------------
// conv 9x9 (64 -> 3) + tanh. Wave per 4 pixels, lane = ci.
__global__ __launch_bounds__(256) void k_conv_out(const float* __restrict__ AT,
        const float* __restrict__ Wo, const float* __restrict__ bias,
        float* __restrict__ out) {
    int t = threadIdx.x;
    int w = t >> 6, lane = t & 63;
    int base = blockIdx.x*16 + w*4;
    int b = base / NSP;
    int n0 = base % NSP;
    int y0 = n0 / WW, x0 = n0 % WW;

    float s[4][3] = {{0,0,0},{0,0,0},{0,0,0},{0,0,0}};
    for (int ky = 0; ky < 9; ++ky) {
        const float* arow = AT + ((size_t)b*PN2 + (size_t)(y0 + ky)*PW2 + x0)*CHN + lane;
        const float* wrow = Wo + (size_t)ky*9*192;
        float xv[12];
        #pragma unroll
        for (int u = 0; u < 12; ++u)
            xv[u] = arow[(size_t)u*CHN];
        #pragma unroll
        for (int kx = 0; kx < 9; ++kx) {
            float w0 = wrow[kx*192 +   0 + lane];
            float w1 = wrow[kx*192 +  64 + lane];
            float w2 = wrow[kx*192 + 128 + lane];
            #pragma unroll
            for (int p = 0; p < 4; ++p) {
                float x = xv[kx + p];
                s[p][0] = fmaf(x, w0, s[p][0]);
                s[p][1] = fmaf(x, w1, s[p][1]);
                s[p][2] = fmaf(x, w2, s[p][2]);
            }
        }
    }
    #pragma unroll
    for (int p = 0; p < 4; ++p)
        #pragma unroll
        for (int c = 0; c < 3; ++c) {
            float v = s[p][c];
            v += __shfl_xor(v, 1);
            v += __shfl_xor(v, 2);
            v += __shfl_xor(v, 4);
            v += __shfl_xor(v, 8);
            v += __shfl_xor(v, 16);
            v += __shfl_xor(v, 32);
            s[p][c] = v;
        }
    #pragma unroll
    for (int p = 0; p < 4; ++p)
        #pragma unroll
        for (int c = 0; c < 3; ++c)
            if (lane == p*3 + c)
                out[((size_t)(b*3 + c))*NSP + n0 + p] = tanhf(s[p][c] + bias[c]);
}

// ---------------------------------------------------------------------------
extern "C" void kernel_launch(void* const* d_in, const int* in_sizes, int n_in,
                              void* d_out, int out_size, void* d_ws, size_t ws_size,
                              hipStream_t stream) {
    (void)in_sizes; (void)n_in; (void)out_size; (void)ws_size;
    const float* x     = (const float*)d_in[0];
    const float* w_in  = (const float*)d_in[1];
    const float* b_in  = (const float*)d_in[2];
    const float* a_in  = (const float*)d_in[3];
    const float* rw1   = (const float*)d_in[4];
    const float* rb1   = (const float*)d_in[5];
    const float* ra    = (const float*)d_in[6];
    const float* rw2   = (const float*)d_in[7];
    const float* rb2   = (const float*)d_in[8];
    const float* wq    = (const float*)d_in[9];
    const float* bq    = (const float*)d_in[10];
    const float* wk    = (const float*)d_in[11];
    const float* bk    = (const float*)d_in[12];
    const float* wv    = (const float*)d_in[13];
    const float* bv    = (const float*)d_in[14];
    const float* gamma = (const float*)d_in[15];
    const float* w_out = (const float*)d_in[16];
    const float* b_out = (const float*)d_in[17];

    const size_t SZ_FR  = (size_t)BATCH*PN*CHN*4;        // 4,917,248
    const size_t SZ_FBI = (size_t)BATCH*FBST*2;          // 5,048,320
    const size_t SZ_WT  = (size_t)NBLK*2*9*CHN*CHN*2;    //   737,280
    const size_t SZ_QK  = (size_t)BATCH*NSP*C8*2;        //   294,912
    const size_t SZ_VB  = (size_t)BATCH*CHN*NSP*2;       // 2,359,296
    const size_t SZ_AT  = (size_t)BATCH*PN2*CHN*4;       // 5,537,792
    const size_t SZ_WO  = (size_t)81*CIN*CHN*4;          //    62,208
    const size_t SZ_WIN = (size_t)243*CHN*4;             //    62,208
    const size_t SZ_WQ  = (size_t)80*CHN*2;              //    10,240
    const size_t SZ_OP  = (size_t)BATCH*NRB*2*32*64*4;   // 18,874,368
    const size_t SZ_LG  = (size_t)BATCH*NRB*2*32*4;      //   147,456
    char* p = (char*)d_ws;
    float* FR      = (float*)p;           p += SZ_FR;
    short* FBI0raw = (short*)p;           p += SZ_FBI;
    short* FBI1raw = (short*)p;           p += SZ_FBI;
    short* Whi     = (short*)p;           p += SZ_WT;
    short* Wlo     = (short*)p;           p += SZ_WT;
    short* Qb16    = (short*)p;           p += SZ_QK;
    short* Kb16    = (short*)p;           p += SZ_QK;
    short* Vb16    = (short*)p;           p += SZ_VB;
    float* AT      = (float*)p;           p += SZ_AT;
    float* Wo      = (float*)p;           p += SZ_WO;
    float* Win     = (float*)p;           p += SZ_WIN;
    short* Wqh     = (short*)p;           p += SZ_WQ;
    short* Wql     = (short*)p;           p += SZ_WQ;
    float* Opg     = (float*)p;           p += SZ_OP;
    float* lgb     = (float*)p;           p += SZ_LG;
    float* Kinf    = (float*)p;           p += 32;
    short* FBI0 = FBI0raw + (size_t)GUARD*128;
    short* FBI1 = FBI1raw + (size_t)GUARD*128;
    float* outp = (float*)d_out;

    hipMemsetAsync(FR, 0, SZ_FR, stream);
    hipMemsetAsync(FBI0raw, 0, SZ_FBI, stream);
    hipMemsetAsync(FBI1raw, 0, SZ_FBI, stream);
    hipMemsetAsync(AT, 0, SZ_AT, stream);
    hipMemsetAsync(Kinf, 0, 32, stream);

    dim3 blk(256);

    k_prep_w<<<(NBLK*2*9*CHN*CHN + 255)/256, blk, 0, stream>>>(rw1, rw2, Whi, Wlo);
    k_prep_wqkv<<<(80*CHN + 255)/256, blk, 0, stream>>>(wq, wk, wv, Wqh, Wql);
    k_prep_wout<<<(81*CIN*CHN + 255)/256, blk, 0, stream>>>(w_out, Wo);
    k_prep_win<<<(243*CHN + 255)/256, blk, 0, stream>>>(w_in, Win);
    k_conv_in<<<BATCH*96*3, blk, 0, stream>>>(x, Win, b_in, a_in, FR, FBI0);
    for (int i = 0; i < NBLK; ++i) {
        k_conv3_mfma<<<BATCH*588, blk, 0, stream>>>(
            FBI0,
            Whi + (size_t)(2*i)*9*CHN*CHN, Wlo + (size_t)(2*i)*9*CHN*CHN,
            rb1 + i*CHN, ra + i, (float*)nullptr, FBI1, 0);
        k_conv3_mfma<<<BATCH*588, blk, 0, stream>>>(
            FBI1,
            Whi + (size_t)(2*i+1)*9*CHN*CHN, Wlo + (size_t)(2*i+1)*9*CHN*CHN,
            rb2 + i*CHN, ra + i, FR, FBI0, 1);
    }
    k_qkv_mfma<<<BATCH*147, blk, 0, stream>>>(
        FBI0, Wqh, Wql, bq, bk, bv, Qb16, Kb16, Vb16, Kinf);
    k_attn_mfma<<<BATCH*NRB*2, blk, 0, stream>>>(
        Qb16, Kb16, Vb16, Kinf, Opg, lgb);
    k_attn_fin<<<BATCH*NRB, blk, 0, stream>>>(Opg, lgb, FR, gamma, AT);
    k_conv_out<<<(BATCH*NSP)/16, blk, 0, stream>>>(AT, Wo, b_out, outp);
}

// Round 14
// 703.377 us; speedup vs baseline: 7.1489x; 1.1453x over previous
//
#include <hip/hip_runtime.h>
#include <cmath>

#define BATCH 2
#define CIN 3
#define HH 96
#define WW 96
#define NSP (HH*WW)      // 9216
#define CHN 64
#define C8 8
#define NBLK 5

#define PW 98            // padded width/height (3x3 convs)
#define PN (PW*PW)       // 9604 padded spatial
#define GUARD 128        // guard rows (spatial) each side of FBI buffers
#define FBST ((PN + 2*GUARD)*128)  // shorts per batch in FBI (hi|lo interleaved)

#define PW2 104          // padded width for 9x9 conv_out input
#define PN2 (PW2*PW2)    // 10816

#define NRB (NSP/32)     // 288 row-blocks in attention

#define LOG2E 1.4426950408889634f
#define BOOST 100.0f     // exponent boost: p' = 2^(e-M+BOOST), overflow-safe

typedef __attribute__((ext_vector_type(8))) short bf16x8;
typedef __attribute__((ext_vector_type(4))) float f32x4;

static __device__ __forceinline__ short f2b(float f) {
    union { float f; unsigned u; } v; v.f = f;
    unsigned r = (v.u + 0x7FFFu + ((v.u >> 16) & 1u)) >> 16;
    return (short)r;
}
static __device__ __forceinline__ float b2f(short s) {
    union { unsigned u; float f; } v; v.u = ((unsigned)(unsigned short)s) << 16;
    return v.f;
}
static __device__ __forceinline__ void split2(float v, short& hi, short& lo) {
    hi = f2b(v);
    lo = f2b(v - b2f(hi));
}

// ---------------------------------------------------------------------------
// weight prep: rw[blk][co][ci][3][3] fp32 -> Whi/Wlo[conv][kyx][co][ci] bf16
__global__ __launch_bounds__(256) void k_prep_w(const float* __restrict__ rw1,
        const float* __restrict__ rw2, short* __restrict__ Whi,
        short* __restrict__ Wlo) {
    int idx = blockIdx.x * 256 + threadIdx.x;
    const int TOT = NBLK*2*9*CHN*CHN;
    if (idx >= TOT) return;
    int ci  = idx & 63;
    int co  = (idx >> 6) & 63;
    int kyx = (idx >> 12) % 9;
    int conv = idx / (9*CHN*CHN);
    int blk = conv >> 1, s = conv & 1;
    const float* src = s ? rw2 : rw1;
    float v = src[(((size_t)(blk*CHN + co))*CHN + ci)*9 + kyx];
    short h, l; split2(v, h, l);
    Whi[idx] = h; Wlo[idx] = l;
}

// qkv weight prep: -> Wq[co=0..79][ci] bf16 hi/lo (0-7 wq, 8-15 wk, 16-79 wv)
__global__ __launch_bounds__(256) void k_prep_wqkv(const float* __restrict__ wq,
        const float* __restrict__ wk, const float* __restrict__ wv,
        short* __restrict__ Wh, short* __restrict__ Wl) {
    int idx = blockIdx.x * 256 + threadIdx.x;
    if (idx >= 80*CHN) return;
    int ci = idx & 63, co = idx >> 6;
    float v;
    if (co < 8)       v = wq[co*CHN + ci];
    else if (co < 16) v = wk[(co-8)*CHN + ci];
    else              v = wv[(co-16)*CHN + ci];
    short h, l; split2(v, h, l);
    Wh[idx] = h; Wl[idx] = l;
}

// conv_out weight prep: w_out[co][ci][81] fp32 -> Wo[kyx][co][ci] fp32
__global__ __launch_bounds__(256) void k_prep_wout(const float* __restrict__ w_out,
        float* __restrict__ Wo) {
    int idx = blockIdx.x * 256 + threadIdx.x;
    if (idx >= 81*CIN*CHN) return;
    int ci = idx & 63;
    int co = (idx >> 6) % 3;
    int kyx = idx / 192;
    Wo[idx] = w_out[((size_t)(co*CHN + ci))*81 + kyx];
}

// conv_in weight prep: w_in[co][ci][81] fp32 -> Win[k=ci*81+kyx][co] fp32
__global__ __launch_bounds__(256) void k_prep_win(const float* __restrict__ w_in,
        float* __restrict__ Win) {
    int idx = blockIdx.x * 256 + threadIdx.x;
    if (idx >= 243*CHN) return;
    int co = idx & 63;
    int k  = idx >> 6;          // 0..242
    int ci = k / 81, kk = k % 81;
    Win[idx] = w_in[((size_t)(co*CIN + ci))*81 + kk];
}

// ---------------------------------------------------------------------------
// conv 9x9 (3 -> 64), pad 4, + PReLU, two-phase (rolled ci/ky loops).
__global__ __launch_bounds__(256) void k_conv_in(const float* __restrict__ x,
        const float* __restrict__ Win, const float* __restrict__ bias,
        const float* __restrict__ a, float* __restrict__ FR,
        short* __restrict__ FBI) {
    __shared__ float Ls[32][65];
    int t = threadIdx.x;
    int blk = blockIdx.x;            // b*288 + y*3 + xc
    int b  = blk / 288;
    int y  = (blk % 288) / 3;
    int xc = blk % 3;
    int x0 = xc*32;
    int px  = t & 31;
    int cog = t >> 5;                // co group: co = cog*8 + r
    int xx = x0 + px;

    float acc[8];
    #pragma unroll
    for (int r = 0; r < 8; ++r) acc[r] = bias[cog*8 + r];

    #pragma unroll 1
    for (int ci = 0; ci < CIN; ++ci) {
        const float* xin = x + ((size_t)(b*CIN + ci))*NSP;
        #pragma unroll 1
        for (int ky = 0; ky < 9; ++ky) {
            int yy = y + ky - 4;
            bool vy = (yy >= 0 && yy < 96);
            float xv[9];
            #pragma unroll
            for (int kx = 0; kx < 9; ++kx) {
                int xs = xx - 4 + kx;
                xv[kx] = (vy && xs >= 0 && xs < 96) ? xin[yy*96 + xs] : 0.f;
            }
            const float* wrow = Win + (size_t)(ci*81 + ky*9)*64 + cog*8;
            #pragma unroll
            for (int kx = 0; kx < 9; ++kx) {
                float4 w0 = *(const float4*)(wrow + kx*64);
                float4 w1 = *(const float4*)(wrow + kx*64 + 4);
                float xvk = xv[kx];
                acc[0] = fmaf(xvk, w0.x, acc[0]);
                acc[1] = fmaf(xvk, w0.y, acc[1]);
                acc[2] = fmaf(xvk, w0.z, acc[2]);
                acc[3] = fmaf(xvk, w0.w, acc[3]);
                acc[4] = fmaf(xvk, w1.x, acc[4]);
                acc[5] = fmaf(xvk, w1.y, acc[5]);
                acc[6] = fmaf(xvk, w1.z, acc[6]);
                acc[7] = fmaf(xvk, w1.w, acc[7]);
            }
        }
    }
    float sl = a[0];
    #pragma unroll
    for (int r = 0; r < 8; ++r) {
        float v = acc[r];
        Ls[px][cog*8 + r] = v >= 0.f ? v : sl*v;
    }
    __syncthreads();

    int p = t >> 3, coq = (t & 7)*8;
    int np = (y + 1)*PW + x0 + p + 1;
    float v[8];
    #pragma unroll
    for (int u = 0; u < 8; ++u) v[u] = Ls[p][coq + u];
    float* fr = FR + ((size_t)b*PN + np)*CHN + coq;
    *(float4*)fr       = make_float4(v[0], v[1], v[2], v[3]);
    *(float4*)(fr + 4) = make_float4(v[4], v[5], v[6], v[7]);
    union { short s[8]; bf16x8 v8; } hu, lu;
    #pragma unroll
    for (int u = 0; u < 8; ++u) split2(v[u], hu.s[u], lu.s[u]);
    short* fo = FBI + (size_t)b*FBST + (size_t)np*128;
    *(bf16x8*)(fo + coq)      = hu.v8;
    *(bf16x8*)(fo + 64 + coq) = lu.v8;
}

// ---------------------------------------------------------------------------
// 3x3 conv 64->64, implicit GEMM, split-bf16 3-MFMA, LDS-staged activations.
// Block = (row y, 32-px x-chunk) x 64 co; window 3 rows x 36 px x 256 B
// = 27.6 KB staged once (coalesced, independent loads). Granule XOR-swizzle
// (G ^= px&15) makes all compute ds_read_b128 2-way conflict-free (m136).
// No boundary checks needed: all 32 outputs are interior to the padded frame.
__global__ __launch_bounds__(256, 4) void k_conv3_mfma(
        const short* __restrict__ FBin,
        const short* __restrict__ Whi, const short* __restrict__ Wlo,
        const float* __restrict__ bias, const float* __restrict__ slope_p,
        float* __restrict__ FR, short* __restrict__ FBout, int mode) {
    __shared__ short xs[3*36*128];   // 27,648 B
    char* xb = (char*)xs;
    int t = threadIdx.x;
    int w = t >> 6, lane = t & 63;
    int q = lane >> 4, n16 = lane & 15;
    int blk = blockIdx.x;
    int b  = blk / 288;
    int y  = (blk % 288) / 3;
    int xc = blk % 3;
    int x0 = xc*32;

    const short* fbB = FBin + (size_t)b*FBST;

    // ---- stage: 1728 16-B granules, swizzled into LDS ----
    #pragma unroll
    for (int k = 0; k < 7; ++k) {
        int u = k*256 + t;
        if (u < 1728) {
            int px_lin = u >> 4, G = u & 15;
            int r = px_lin / 36, p = px_lin - r*36;
            const float4 src = *(const float4*)(fbB
                + ((size_t)((y + r)*PW + x0 + p))*128 + G*8);
            *(float4*)(xb + (px_lin << 8) + ((G ^ (px_lin & 15)) << 4)) = src;
        }
    }
    __syncthreads();

    // ---- compute: wave = 16 sp x 32 co ----
    int sphalf = w >> 1;
    int cth = (w & 1)*2;                 // ct tiles cth, cth+1
    int opx = sphalf*16 + n16;           // output px 0..31
    f32x4 acc[2] = {{0,0,0,0},{0,0,0,0}};

    #pragma unroll
    for (int dy = 0; dy < 3; ++dy) {
        #pragma unroll
        for (int dx = 0; dx < 3; ++dx) {
            int kyx = dy*3 + dx;
            int px_lin = dy*36 + opx + dx;
            int pbase = px_lin << 8;
            int sw = (px_lin & 15);
            const short* wp_h = Whi + (size_t)kyx*CHN*CHN;
            const short* wp_l = Wlo + (size_t)kyx*CHN*CHN;
            #pragma unroll
            for (int cih = 0; cih < 2; ++cih) {
                int Gh = cih*4 + q;
                int Gl = 8 + cih*4 + q;
                bf16x8 bhi = *(const bf16x8*)(xb + pbase + ((Gh ^ sw) << 4));
                bf16x8 blo = *(const bf16x8*)(xb + pbase + ((Gl ^ sw) << 4));
                #pragma unroll
                for (int ctl = 0; ctl < 2; ++ctl) {
                    int aoff = ((cth + ctl)*16 + n16)*CHN + cih*32 + q*8;
                    bf16x8 ahi = *(const bf16x8*)(wp_h + aoff);
                    bf16x8 alo = *(const bf16x8*)(wp_l + aoff);
                    acc[ctl] = __builtin_amdgcn_mfma_f32_16x16x32_bf16(ahi, bhi, acc[ctl], 0, 0, 0);
                    acc[ctl] = __builtin_amdgcn_mfma_f32_16x16x32_bf16(ahi, blo, acc[ctl], 0, 0, 0);
                    acc[ctl] = __builtin_amdgcn_mfma_f32_16x16x32_bf16(alo, bhi, acc[ctl], 0, 0, 0);
                }
            }
        }
    }

    // ---- epilogue: all outputs interior, no checks ----
    int nb = (y + 1)*PW + x0 + 1 + opx;
    float sl = slope_p[0];
    short* fbo = FBout + (size_t)b*FBST + (size_t)nb*128;
    float* fr  = FR + ((size_t)b*PN + nb)*CHN;
    #pragma unroll
    for (int ctl = 0; ctl < 2; ++ctl) {
        #pragma unroll
        for (int r = 0; r < 4; ++r) {
            int co = (cth + ctl)*16 + q*4 + r;
            float v = acc[ctl][r] + bias[co];
            if (mode == 0) {
                v = v >= 0.f ? v : sl*v;
            } else {
                v += fr[co];
                fr[co] = v;
            }
            short h, l; split2(v, h, l);
            fbo[co]      = h;
            fbo[64 + co] = l;
        }
    }
}

// ---------------------------------------------------------------------------
// qkv projection as 1x1-conv implicit GEMM (80 outputs = 8 q + 8 k + 64 v).
__global__ __launch_bounds__(256) void k_qkv_mfma(
        const short* __restrict__ FBin,
        const short* __restrict__ Wh, const short* __restrict__ Wl,
        const float* __restrict__ bq, const float* __restrict__ bk,
        const float* __restrict__ bv,
        short* __restrict__ Qb, short* __restrict__ Kb, short* __restrict__ Vb,
        float* __restrict__ Kinf) {
    int t = threadIdx.x;
    int w = t >> 6, lane = t & 63;
    int q = lane >> 4, n16 = lane & 15;
    int blk = blockIdx.x;
    int b = blk / 147, chunk = blk % 147;
    int nb = 98 + chunk*64 + w*16 + n16;

    const short* fb = FBin + (size_t)b*FBST;
    f32x4 acc[5] = {{0,0,0,0},{0,0,0,0},{0,0,0,0},{0,0,0,0},{0,0,0,0}};

    int nbase = nb*128;
    #pragma unroll
    for (int cih = 0; cih < 2; ++cih) {
        bf16x8 bhi = *(const bf16x8*)(fb + nbase + cih*32 + q*8);
        bf16x8 blo = *(const bf16x8*)(fb + nbase + 64 + cih*32 + q*8);
        #pragma unroll
        for (int ct = 0; ct < 5; ++ct) {
            int aoff = (ct*16 + n16)*CHN + cih*32 + q*8;
            bf16x8 ahi = *(const bf16x8*)(Wh + aoff);
            bf16x8 alo = *(const bf16x8*)(Wl + aoff);
            acc[ct] = __builtin_amdgcn_mfma_f32_16x16x32_bf16(ahi, bhi, acc[ct], 0, 0, 0);
            acc[ct] = __builtin_amdgcn_mfma_f32_16x16x32_bf16(ahi, blo, acc[ct], 0, 0, 0);
            acc[ct] = __builtin_amdgcn_mfma_f32_16x16x32_bf16(alo, bhi, acc[ct], 0, 0, 0);
        }
    }

    int yy = nb / PW;
    int xx = nb - yy*PW;
    float kabs[4] = {0.f, 0.f, 0.f, 0.f};
    if (xx >= 1 && xx <= 96 && yy >= 1 && yy <= 96) {
        int n = (yy - 1)*WW + (xx - 1);
        #pragma unroll
        for (int ct = 0; ct < 5; ++ct) {
            #pragma unroll
            for (int r = 0; r < 4; ++r) {
                int co = ct*16 + q*4 + r;
                float v = acc[ct][r];
                if (co < 8)
                    Qb[((size_t)b*NSP + n)*8 + co] = f2b((v + bq[co]) * LOG2E);
                else if (co < 16) {
                    float kv = v + bk[co-8];
                    kabs[r] = fabsf(kv) * 1.01f;
                    Kb[((size_t)b*NSP + n)*8 + (co-8)] = f2b(kv);
                } else
                    Vb[((size_t)(b*CHN + co-16))*NSP + n] = f2b(v + bv[co-16]);
            }
        }
    }
    #pragma unroll
    for (int r = 0; r < 4; ++r) {
        #pragma unroll
        for (int off = 1; off < 16; off <<= 1)
            kabs[r] = fmaxf(kabs[r], __shfl_xor(kabs[r], off));
    }
    if (q >= 2 && n16 == 0) {
        #pragma unroll
        for (int r = 0; r < 4; ++r)
            atomicMax((int*)&Kinf[(q - 2)*4 + r], __float_as_int(kabs[r]));
    }
}

// ---------------------------------------------------------------------------
// chunk buffer for attention double-buffering (compile-time indices only).
struct CB { bf16x8 kf[4]; bf16x8 vf[8]; };

static __device__ __forceinline__ void attn_load(CB& cb,
        const short* __restrict__ Kp, const short* __restrict__ Vp,
        int j0, int quad, int n16, int krow_base) {
    #pragma unroll
    for (int tt = 0; tt < 4; ++tt) {
        bf16x8 z = {0,0,0,0,0,0,0,0};
        cb.kf[tt] = z;
        if (quad == 0) {
            int jrow = j0 + (tt >> 1)*32 + (tt & 1)*4 + krow_base;
            cb.kf[tt] = *(const bf16x8*)(Kp + (size_t)jrow*8);
        }
    }
    #pragma unroll
    for (int ks = 0; ks < 2; ++ks)
        #pragma unroll
        for (int ct = 0; ct < 4; ++ct)
            cb.vf[ks*4 + ct] = *(const bf16x8*)(Vp + (size_t)(ct*16 + n16)*NSP
                                                + j0 + ks*32 + quad*8);
}

static __device__ __forceinline__ void attn_compute(const CB& cb,
        const bf16x8 (&qf)[2], const f32x4 (&ci)[2],
        f32x4 (&accO)[2][4], float (&lp)[2]) {
    f32x4 e[2][4];
    #pragma unroll
    for (int rg = 0; rg < 2; ++rg)
        #pragma unroll
        for (int tt = 0; tt < 4; ++tt)
            e[rg][tt] = __builtin_amdgcn_mfma_f32_16x16x32_bf16(cb.kf[tt], qf[rg], ci[rg], 0, 0, 0);
    #pragma unroll
    for (int rg = 0; rg < 2; ++rg) {
        float s = 0.f;
        #pragma unroll
        for (int tt = 0; tt < 4; ++tt)
            #pragma unroll
            for (int r = 0; r < 4; ++r) {
                float p = __builtin_amdgcn_exp2f(e[rg][tt][r]);
                e[rg][tt][r] = p;
                s += p;
            }
        lp[rg] += s;
    }
    #pragma unroll
    for (int ks = 0; ks < 2; ++ks) {
        #pragma unroll
        for (int rg = 0; rg < 2; ++rg) {
            union { int di[4]; bf16x8 v8; } pu;
            int t2 = ks*2;
            pu.di[0] = __builtin_amdgcn_perm(__float_as_uint(e[rg][t2][1]),
                                             __float_as_uint(e[rg][t2][0]), 0x07060302u);
            pu.di[1] = __builtin_amdgcn_perm(__float_as_uint(e[rg][t2][3]),
                                             __float_as_uint(e[rg][t2][2]), 0x07060302u);
            pu.di[2] = __builtin_amdgcn_perm(__float_as_uint(e[rg][t2+1][1]),
                                             __float_as_uint(e[rg][t2+1][0]), 0x07060302u);
            pu.di[3] = __builtin_amdgcn_perm(__float_as_uint(e[rg][t2+1][3]),
                                             __float_as_uint(e[rg][t2+1][2]), 0x07060302u);
            #pragma unroll
            for (int ct = 0; ct < 4; ++ct)
                accO[rg][ct] = __builtin_amdgcn_mfma_f32_16x16x32_bf16(
                    pu.v8, cb.vf[ks*4 + ct], accO[rg][ct], 0, 0, 0);
        }
    }
}

// MFMA flash attention, bound-based softmax, j-split across 2 blocks,
// register double-buffered K/V prefetch with compile-time buffer selection.
__global__ __launch_bounds__(256) void k_attn_mfma(
        const short* __restrict__ Qb, const short* __restrict__ Kb,
        const short* __restrict__ Vb, const float* __restrict__ Kinf_p,
        float* __restrict__ Opg, float* __restrict__ lg) {
    __shared__ float Opart[4][2][16][68];
    __shared__ float lsh[4][2][16];

    int blk = blockIdx.x;
    int b    = blk / (NRB*2);
    int rb   = (blk % (NRB*2)) >> 1;
    int half = blk & 1;
    int i0 = rb*32;
    int t = threadIdx.x;
    int w = t >> 6;
    int lane = t & 63;
    int quad = lane >> 4, n16 = lane & 15;

    const short* Qp = Qb + ((size_t)b*NSP)*8;
    const short* Kp = Kb + ((size_t)b*NSP)*8;
    const short* Vp = Vb + ((size_t)b*CHN)*NSP;

    bf16x8 qf[2];
    float Mi[2];
    #pragma unroll
    for (int rg = 0; rg < 2; ++rg) {
        bf16x8 z = {0,0,0,0,0,0,0,0};
        qf[rg] = z;
        if (quad == 0)
            qf[rg] = *(const bf16x8*)(Qp + (size_t)(i0 + rg*16 + n16)*8);
        float s1 = 0.f;
        #pragma unroll
        for (int c = 0; c < 8; ++c)
            s1 += fabsf(b2f(qf[rg][c])) * Kinf_p[c];
        float Mv = s1 + 1.0f - BOOST;
        Mi[rg] = __shfl(Mv, n16);
    }

    f32x4 accO[2][4] = {{{0,0,0,0},{0,0,0,0},{0,0,0,0},{0,0,0,0}},
                        {{0,0,0,0},{0,0,0,0},{0,0,0,0},{0,0,0,0}}};
    float lp[2] = {0.f, 0.f};
    f32x4 ci[2];
    #pragma unroll
    for (int rg = 0; rg < 2; ++rg) {
        ci[rg][0] = -Mi[rg]; ci[rg][1] = -Mi[rg];
        ci[rg][2] = -Mi[rg]; ci[rg][3] = -Mi[rg];
    }

    int krow_base = (n16 >> 2)*8 + (n16 & 3);
    int jbase = half*4608 + w*1152;

    CB bufA, bufB;
    attn_load(bufA, Kp, Vp, jbase, quad, n16, krow_base);

    #pragma unroll 1
    for (int jc = 0; jc < 18; jc += 2) {
        attn_load(bufB, Kp, Vp, jbase + (jc + 1)*64, quad, n16, krow_base);
        attn_compute(bufA, qf, ci, accO, lp);
        if (jc + 2 < 18)
            attn_load(bufA, Kp, Vp, jbase + (jc + 2)*64, quad, n16, krow_base);
        attn_compute(bufB, qf, ci, accO, lp);
    }

    #pragma unroll
    for (int rg = 0; rg < 2; ++rg) {
        float l = lp[rg];
        l += __shfl_xor(l, 16);
        l += __shfl_xor(l, 32);
        if (quad == 0) lsh[w][rg][n16] = l;
        #pragma unroll
        for (int ct = 0; ct < 4; ++ct)
            #pragma unroll
            for (int r = 0; r < 4; ++r)
                Opart[w][rg][quad*4 + r][ct*16 + n16] = accO[rg][ct][r];
    }
    __syncthreads();

    int row = t >> 3;            // 0..31
    int rg = row >> 4, ii = row & 15;
    int c0 = (t & 7)*8;
    size_t obase = (((size_t)(b*NRB + rb))*2 + half)*2048 + (size_t)row*64;
    #pragma unroll
    for (int cc = 0; cc < 8; ++cc) {
        int c = c0 + cc;
        Opg[obase + c] = Opart[0][rg][ii][c] + Opart[1][rg][ii][c]
                       + Opart[2][rg][ii][c] + Opart[3][rg][ii][c];
    }
    if ((t & 7) == 0)
        lg[(((size_t)(b*NRB + rb))*2 + half)*32 + row] =
            lsh[0][rg][ii] + lsh[1][rg][ii] + lsh[2][rg][ii] + lsh[3][rg][ii];
}

// ---------------------------------------------------------------------------
// attention finalize: merge 2 j-halves, normalize, add residual, write AT.
__global__ __launch_bounds__(256) void k_attn_fin(
        const float* __restrict__ Opg, const float* __restrict__ lg,
        const float* __restrict__ FR, const float* __restrict__ gamma_p,
        float* __restrict__ AT) {
    int blk = blockIdx.x;            // b*NRB + rb
    int b = blk / NRB, rb = blk % NRB;
    int t = threadIdx.x;
    int row = t >> 3;
    int c0 = (t & 7)*8;
    float g = gamma_p[0];
    size_t ob = ((size_t)blk*2)*2048 + (size_t)row*64;
    float l0 = lg[((size_t)blk*2)*32 + row];
    float l1 = lg[((size_t)blk*2 + 1)*32 + row];
    float inv = g / fmaxf(l0 + l1, 1e-35f);
    int gi = rb*32 + row;
    int iy = gi / WW, ix = gi - iy*WW;
    size_t frb = ((size_t)b*PN + (iy + 1)*PW + ix + 1)*CHN;
    size_t atb = ((size_t)b*PN2 + (iy + 4)*PW2 + ix + 4)*CHN;
    #pragma unroll
    for (int cc = 0; cc < 8; ++cc) {
        int c = c0 + cc;
        float Ov = Opg[ob + c] + Opg[ob + 2048 + c];
        AT[atb + c] = Ov*inv + FR[frb + c];
    }
}

// ---------------------------------------------------------------------------
// conv 9x9 (64 -> 3) + tanh. Wave per 4 pixels, lane = ci.
__global__ __launch_bounds__(256) void k_conv_out(const float* __restrict__ AT,
        const float* __restrict__ Wo, const float* __restrict__ bias,
        float* __restrict__ out) {
    int t = threadIdx.x;
    int w = t >> 6, lane = t & 63;
    int base = blockIdx.x*16 + w*4;
    int b = base / NSP;
    int n0 = base % NSP;
    int y0 = n0 / WW, x0 = n0 % WW;

    float s[4][3] = {{0,0,0},{0,0,0},{0,0,0},{0,0,0}};
    for (int ky = 0; ky < 9; ++ky) {
        const float* arow = AT + ((size_t)b*PN2 + (size_t)(y0 + ky)*PW2 + x0)*CHN + lane;
        const float* wrow = Wo + (size_t)ky*9*192;
        float xv[12];
        #pragma unroll
        for (int u = 0; u < 12; ++u)
            xv[u] = arow[(size_t)u*CHN];
        #pragma unroll
        for (int kx = 0; kx < 9; ++kx) {
            float w0 = wrow[kx*192 +   0 + lane];
            float w1 = wrow[kx*192 +  64 + lane];
            float w2 = wrow[kx*192 + 128 + lane];
            #pragma unroll
            for (int p = 0; p < 4; ++p) {
                float x = xv[kx + p];
                s[p][0] = fmaf(x, w0, s[p][0]);
                s[p][1] = fmaf(x, w1, s[p][1]);
                s[p][2] = fmaf(x, w2, s[p][2]);
            }
        }
    }
    #pragma unroll
    for (int p = 0; p < 4; ++p)
        #pragma unroll
        for (int c = 0; c < 3; ++c) {
            float v = s[p][c];
            v += __shfl_xor(v, 1);
            v += __shfl_xor(v, 2);
            v += __shfl_xor(v, 4);
            v += __shfl_xor(v, 8);
            v += __shfl_xor(v, 16);
            v += __shfl_xor(v, 32);
            s[p][c] = v;
        }
    #pragma unroll
    for (int p = 0; p < 4; ++p)
        #pragma unroll
        for (int c = 0; c < 3; ++c)
            if (lane == p*3 + c)
                out[((size_t)(b*3 + c))*NSP + n0 + p] = tanhf(s[p][c] + bias[c]);
}

// ---------------------------------------------------------------------------
extern "C" void kernel_launch(void* const* d_in, const int* in_sizes, int n_in,
                              void* d_out, int out_size, void* d_ws, size_t ws_size,
                              hipStream_t stream) {
    (void)in_sizes; (void)n_in; (void)out_size; (void)ws_size;
    const float* x     = (const float*)d_in[0];
    const float* w_in  = (const float*)d_in[1];
    const float* b_in  = (const float*)d_in[2];
    const float* a_in  = (const float*)d_in[3];
    const float* rw1   = (const float*)d_in[4];
    const float* rb1   = (const float*)d_in[5];
    const float* ra    = (const float*)d_in[6];
    const float* rw2   = (const float*)d_in[7];
    const float* rb2   = (const float*)d_in[8];
    const float* wq    = (const float*)d_in[9];
    const float* bq    = (const float*)d_in[10];
    const float* wk    = (const float*)d_in[11];
    const float* bk    = (const float*)d_in[12];
    const float* wv    = (const float*)d_in[13];
    const float* bv    = (const float*)d_in[14];
    const float* gamma = (const float*)d_in[15];
    const float* w_out = (const float*)d_in[16];
    const float* b_out = (const float*)d_in[17];

    const size_t SZ_FR  = (size_t)BATCH*PN*CHN*4;        // 4,917,248
    const size_t SZ_FBI = (size_t)BATCH*FBST*2;          // 5,048,320
    const size_t SZ_WT  = (size_t)NBLK*2*9*CHN*CHN*2;    //   737,280
    const size_t SZ_QK  = (size_t)BATCH*NSP*C8*2;        //   294,912
    const size_t SZ_VB  = (size_t)BATCH*CHN*NSP*2;       // 2,359,296
    const size_t SZ_AT  = (size_t)BATCH*PN2*CHN*4;       // 5,537,792
    const size_t SZ_WO  = (size_t)81*CIN*CHN*4;          //    62,208
    const size_t SZ_WIN = (size_t)243*CHN*4;             //    62,208
    const size_t SZ_WQ  = (size_t)80*CHN*2;              //    10,240
    const size_t SZ_OP  = (size_t)BATCH*NRB*2*32*64*4;   // 18,874,368
    const size_t SZ_LG  = (size_t)BATCH*NRB*2*32*4;      //   147,456
    char* p = (char*)d_ws;
    float* FR      = (float*)p;           p += SZ_FR;
    short* FBI0raw = (short*)p;           p += SZ_FBI;
    short* FBI1raw = (short*)p;           p += SZ_FBI;
    short* Whi     = (short*)p;           p += SZ_WT;
    short* Wlo     = (short*)p;           p += SZ_WT;
    short* Qb16    = (short*)p;           p += SZ_QK;
    short* Kb16    = (short*)p;           p += SZ_QK;
    short* Vb16    = (short*)p;           p += SZ_VB;
    float* AT      = (float*)p;           p += SZ_AT;
    float* Wo      = (float*)p;           p += SZ_WO;
    float* Win     = (float*)p;           p += SZ_WIN;
    short* Wqh     = (short*)p;           p += SZ_WQ;
    short* Wql     = (short*)p;           p += SZ_WQ;
    float* Opg     = (float*)p;           p += SZ_OP;
    float* lgb     = (float*)p;           p += SZ_LG;
    float* Kinf    = (float*)p;           p += 32;
    short* FBI0 = FBI0raw + (size_t)GUARD*128;
    short* FBI1 = FBI1raw + (size_t)GUARD*128;
    float* outp = (float*)d_out;

    hipMemsetAsync(FR, 0, SZ_FR, stream);
    hipMemsetAsync(FBI0raw, 0, SZ_FBI, stream);
    hipMemsetAsync(FBI1raw, 0, SZ_FBI, stream);
    hipMemsetAsync(AT, 0, SZ_AT, stream);
    hipMemsetAsync(Kinf, 0, 32, stream);

    dim3 blk(256);

    k_prep_w<<<(NBLK*2*9*CHN*CHN + 255)/256, blk, 0, stream>>>(rw1, rw2, Whi, Wlo);
    k_prep_wqkv<<<(80*CHN + 255)/256, blk, 0, stream>>>(wq, wk, wv, Wqh, Wql);
    k_prep_wout<<<(81*CIN*CHN + 255)/256, blk, 0, stream>>>(w_out, Wo);
    k_prep_win<<<(243*CHN + 255)/256, blk, 0, stream>>>(w_in, Win);
    k_conv_in<<<BATCH*96*3, blk, 0, stream>>>(x, Win, b_in, a_in, FR, FBI0);
    for (int i = 0; i < NBLK; ++i) {
        k_conv3_mfma<<<BATCH*288, blk, 0, stream>>>(
            FBI0,
            Whi + (size_t)(2*i)*9*CHN*CHN, Wlo + (size_t)(2*i)*9*CHN*CHN,
            rb1 + i*CHN, ra + i, (float*)nullptr, FBI1, 0);
        k_conv3_mfma<<<BATCH*288, blk, 0, stream>>>(
            FBI1,
            Whi + (size_t)(2*i+1)*9*CHN*CHN, Wlo + (size_t)(2*i+1)*9*CHN*CHN,
            rb2 + i*CHN, ra + i, FR, FBI0, 1);
    }
    k_qkv_mfma<<<BATCH*147, blk, 0, stream>>>(
        FBI0, Wqh, Wql, bq, bk, bv, Qb16, Kb16, Vb16, Kinf);
    k_attn_mfma<<<BATCH*NRB*2, blk, 0, stream>>>(
        Qb16, Kb16, Vb16, Kinf, Opg, lgb);
    k_attn_fin<<<BATCH*NRB, blk, 0, stream>>>(Opg, lgb, FR, gamma, AT);
    k_conv_out<<<(BATCH*NSP)/16, blk, 0, stream>>>(AT, Wo, b_out, outp);
}

// Round 16
// 630.900 us; speedup vs baseline: 7.9702x; 1.1149x over previous
//
#include <hip/hip_runtime.h>
#include <cmath>

#define BATCH 2
#define CIN 3
#define HH 96
#define WW 96
#define NSP (HH*WW)      // 9216
#define CHN 64
#define C8 8
#define NBLK 5

#define PW 98            // padded width/height (3x3 convs)
#define PN (PW*PW)       // 9604 padded spatial
#define GUARD 128        // guard rows (spatial) each side of FBI buffers
#define FBST ((PN + 2*GUARD)*128)  // shorts per batch in FBI (hi|lo interleaved)

#define PW2 104          // padded width for 9x9 conv_out input
#define PN2 (PW2*PW2)    // 10816

#define NRB (NSP/32)     // 288 row-blocks in attention

#define LOG2E 1.4426950408889634f
#define BOOST 100.0f     // exponent boost: p' = 2^(e-M+BOOST), overflow-safe

typedef __attribute__((ext_vector_type(8))) short bf16x8;
typedef __attribute__((ext_vector_type(4))) float f32x4;

static __device__ __forceinline__ short f2b(float f) {
    union { float f; unsigned u; } v; v.f = f;
    unsigned r = (v.u + 0x7FFFu + ((v.u >> 16) & 1u)) >> 16;
    return (short)r;
}
static __device__ __forceinline__ float b2f(short s) {
    union { unsigned u; float f; } v; v.u = ((unsigned)(unsigned short)s) << 16;
    return v.f;
}
static __device__ __forceinline__ void split2(float v, short& hi, short& lo) {
    hi = f2b(v);
    lo = f2b(v - b2f(hi));
}

// ---------------------------------------------------------------------------
// weight prep: rw[blk][co][ci][3][3] fp32 -> Whi/Wlo[conv][kyx][co][ci] bf16
__global__ __launch_bounds__(256) void k_prep_w(const float* __restrict__ rw1,
        const float* __restrict__ rw2, short* __restrict__ Whi,
        short* __restrict__ Wlo) {
    int idx = blockIdx.x * 256 + threadIdx.x;
    const int TOT = NBLK*2*9*CHN*CHN;
    if (idx >= TOT) return;
    int ci  = idx & 63;
    int co  = (idx >> 6) & 63;
    int kyx = (idx >> 12) % 9;
    int conv = idx / (9*CHN*CHN);
    int blk = conv >> 1, s = conv & 1;
    const float* src = s ? rw2 : rw1;
    float v = src[(((size_t)(blk*CHN + co))*CHN + ci)*9 + kyx];
    short h, l; split2(v, h, l);
    Whi[idx] = h; Wlo[idx] = l;
}

// qkv weight prep: -> Wq[co=0..79][ci] bf16 hi/lo (0-7 wq, 8-15 wk, 16-79 wv)
__global__ __launch_bounds__(256) void k_prep_wqkv(const float* __restrict__ wq,
        const float* __restrict__ wk, const float* __restrict__ wv,
        short* __restrict__ Wh, short* __restrict__ Wl) {
    int idx = blockIdx.x * 256 + threadIdx.x;
    if (idx >= 80*CHN) return;
    int ci = idx & 63, co = idx >> 6;
    float v;
    if (co < 8)       v = wq[co*CHN + ci];
    else if (co < 16) v = wk[(co-8)*CHN + ci];
    else              v = wv[(co-16)*CHN + ci];
    short h, l; split2(v, h, l);
    Wh[idx] = h; Wl[idx] = l;
}

// conv_out weight prep: w_out[co][ci][81] fp32 -> Wo[kyx][co][ci] fp32
__global__ __launch_bounds__(256) void k_prep_wout(const float* __restrict__ w_out,
        float* __restrict__ Wo) {
    int idx = blockIdx.x * 256 + threadIdx.x;
    if (idx >= 81*CIN*CHN) return;
    int ci = idx & 63;
    int co = (idx >> 6) % 3;
    int kyx = idx / 192;
    Wo[idx] = w_out[((size_t)(co*CHN + ci))*81 + kyx];
}

// conv_in weight prep: w_in[co][ci][81] fp32 -> Win[k=ci*81+kyx][co] fp32
__global__ __launch_bounds__(256) void k_prep_win(const float* __restrict__ w_in,
        float* __restrict__ Win) {
    int idx = blockIdx.x * 256 + threadIdx.x;
    if (idx >= 243*CHN) return;
    int co = idx & 63;
    int k  = idx >> 6;          // 0..242
    int ci = k / 81, kk = k % 81;
    Win[idx] = w_in[((size_t)(co*CIN + ci))*81 + kk];
}

// ---------------------------------------------------------------------------
// conv 9x9 (3 -> 64), pad 4, + PReLU, two-phase (rolled ci/ky loops).
__global__ __launch_bounds__(256) void k_conv_in(const float* __restrict__ x,
        const float* __restrict__ Win, const float* __restrict__ bias,
        const float* __restrict__ a, float* __restrict__ FR,
        short* __restrict__ FBI) {
    __shared__ float Ls[32][65];
    int t = threadIdx.x;
    int blk = blockIdx.x;            // b*288 + y*3 + xc
    int b  = blk / 288;
    int y  = (blk % 288) / 3;
    int xc = blk % 3;
    int x0 = xc*32;
    int px  = t & 31;
    int cog = t >> 5;                // co group: co = cog*8 + r
    int xx = x0 + px;

    float acc[8];
    #pragma unroll
    for (int r = 0; r < 8; ++r) acc[r] = bias[cog*8 + r];

    #pragma unroll 1
    for (int ci = 0; ci < CIN; ++ci) {
        const float* xin = x + ((size_t)(b*CIN + ci))*NSP;
        #pragma unroll 1
        for (int ky = 0; ky < 9; ++ky) {
            int yy = y + ky - 4;
            bool vy = (yy >= 0 && yy < 96);
            float xv[9];
            #pragma unroll
            for (int kx = 0; kx < 9; ++kx) {
                int xs = xx - 4 + kx;
                xv[kx] = (vy && xs >= 0 && xs < 96) ? xin[yy*96 + xs] : 0.f;
            }
            const float* wrow = Win + (size_t)(ci*81 + ky*9)*64 + cog*8;
            #pragma unroll
            for (int kx = 0; kx < 9; ++kx) {
                float4 w0 = *(const float4*)(wrow + kx*64);
                float4 w1 = *(const float4*)(wrow + kx*64 + 4);
                float xvk = xv[kx];
                acc[0] = fmaf(xvk, w0.x, acc[0]);
                acc[1] = fmaf(xvk, w0.y, acc[1]);
                acc[2] = fmaf(xvk, w0.z, acc[2]);
                acc[3] = fmaf(xvk, w0.w, acc[3]);
                acc[4] = fmaf(xvk, w1.x, acc[4]);
                acc[5] = fmaf(xvk, w1.y, acc[5]);
                acc[6] = fmaf(xvk, w1.z, acc[6]);
                acc[7] = fmaf(xvk, w1.w, acc[7]);
            }
        }
    }
    float sl = a[0];
    #pragma unroll
    for (int r = 0; r < 8; ++r) {
        float v = acc[r];
        Ls[px][cog*8 + r] = v >= 0.f ? v : sl*v;
    }
    __syncthreads();

    int p = t >> 3, coq = (t & 7)*8;
    int np = (y + 1)*PW + x0 + p + 1;
    float v[8];
    #pragma unroll
    for (int u = 0; u < 8; ++u) v[u] = Ls[p][coq + u];
    float* fr = FR + ((size_t)b*PN + np)*CHN + coq;
    *(float4*)fr       = make_float4(v[0], v[1], v[2], v[3]);
    *(float4*)(fr + 4) = make_float4(v[4], v[5], v[6], v[7]);
    union { short s[8]; bf16x8 v8; } hu, lu;
    #pragma unroll
    for (int u = 0; u < 8; ++u) split2(v[u], hu.s[u], lu.s[u]);
    short* fo = FBI + (size_t)b*FBST + (size_t)np*128;
    *(bf16x8*)(fo + coq)      = hu.v8;
    *(bf16x8*)(fo + 64 + coq) = lu.v8;
}

// ---------------------------------------------------------------------------
// 3x3 conv 64->64, implicit GEMM, split-bf16 3-MFMA, small LDS window for TLP.
// Block = (row y, 16-px x-chunk) x 64 co; window 3 rows x 18 px x 256 B
// = 13.8 KB. Grid 1152 -> 4.5 blocks/CU x 4 waves = 18 waves/CU (2x round 13).
// Wave = 16 px x 16 co (acc = one f32x4, tiny VGPR). Granule XOR-swizzle
// keeps all compute ds_read_b128 at 2-way (free, m136).
// Window cols = x0 .. x0+17 (output col x0+1+n16, taps x0+n16+dx) — the
// round-14 bug was staging x0-1+p (one col left), shifting the whole conv.
__global__ __launch_bounds__(256, 4) void k_conv3_mfma(
        const short* __restrict__ FBin,
        const short* __restrict__ Whi, const short* __restrict__ Wlo,
        const float* __restrict__ bias, const float* __restrict__ slope_p,
        float* __restrict__ FR, short* __restrict__ FBout, int mode) {
    __shared__ short xs[3*18*128];   // 13,824 B
    char* xb = (char*)xs;
    int t = threadIdx.x;
    int w = t >> 6, lane = t & 63;
    int q = lane >> 4, n16 = lane & 15;
    int blk = blockIdx.x;
    int b   = blk / 576;
    int rem = blk % 576;
    int y   = rem / 6;
    int x0  = (rem % 6)*16;

    const short* fbB = FBin + (size_t)b*FBST;

    // ---- stage: 864 16-B granules, swizzled into LDS ----
    #pragma unroll
    for (int k = 0; k < 4; ++k) {
        int u = k*256 + t;
        if (u < 864) {
            int px_lin = u >> 4, G = u & 15;
            int r = px_lin / 18, p = px_lin - r*18;
            const float4 src = *(const float4*)(fbB
                + ((size_t)((y + r)*PW + x0 + p))*128 + G*8);
            *(float4*)(xb + (px_lin << 8) + ((G ^ (px_lin & 15)) << 4)) = src;
        }
    }
    __syncthreads();

    // ---- compute: wave = 16 px x 16 co (ct = w) ----
    int ct = w;
    f32x4 acc = {0,0,0,0};

    #pragma unroll
    for (int dy = 0; dy < 3; ++dy) {
        #pragma unroll
        for (int dx = 0; dx < 3; ++dx) {
            int kyx = dy*3 + dx;
            int px_lin = dy*18 + n16 + dx;
            int pbase = px_lin << 8;
            int sw = px_lin & 15;
            const short* wp_h = Whi + (size_t)kyx*CHN*CHN;
            const short* wp_l = Wlo + (size_t)kyx*CHN*CHN;
            #pragma unroll
            for (int cih = 0; cih < 2; ++cih) {
                int Gh = cih*4 + q;
                int Gl = 8 + cih*4 + q;
                bf16x8 bhi = *(const bf16x8*)(xb + pbase + ((Gh ^ sw) << 4));
                bf16x8 blo = *(const bf16x8*)(xb + pbase + ((Gl ^ sw) << 4));
                int aoff = (ct*16 + n16)*CHN + cih*32 + q*8;
                bf16x8 ahi = *(const bf16x8*)(wp_h + aoff);
                bf16x8 alo = *(const bf16x8*)(wp_l + aoff);
                acc = __builtin_amdgcn_mfma_f32_16x16x32_bf16(ahi, bhi, acc, 0, 0, 0);
                acc = __builtin_amdgcn_mfma_f32_16x16x32_bf16(ahi, blo, acc, 0, 0, 0);
                acc = __builtin_amdgcn_mfma_f32_16x16x32_bf16(alo, bhi, acc, 0, 0, 0);
            }
        }
    }

    // ---- epilogue: all outputs interior, no checks ----
    int nb = (y + 1)*PW + x0 + 1 + n16;
    float sl = slope_p[0];
    short* fbo = FBout + (size_t)b*FBST + (size_t)nb*128;
    float* fr  = FR + ((size_t)b*PN + nb)*CHN;
    #pragma unroll
    for (int r = 0; r < 4; ++r) {
        int co = ct*16 + q*4 + r;
        float v = acc[r] + bias[co];
        if (mode == 0) {
            v = v >= 0.f ? v : sl*v;
        } else {
            v += fr[co];
            fr[co] = v;
        }
        short h, l; split2(v, h, l);
        fbo[co]      = h;
        fbo[64 + co] = l;
    }
}

// ---------------------------------------------------------------------------
// qkv projection as 1x1-conv implicit GEMM (80 outputs = 8 q + 8 k + 64 v).
__global__ __launch_bounds__(256) void k_qkv_mfma(
        const short* __restrict__ FBin,
        const short* __restrict__ Wh, const short* __restrict__ Wl,
        const float* __restrict__ bq, const float* __restrict__ bk,
        const float* __restrict__ bv,
        short* __restrict__ Qb, short* __restrict__ Kb, short* __restrict__ Vb,
        float* __restrict__ Kinf) {
    int t = threadIdx.x;
    int w = t >> 6, lane = t & 63;
    int q = lane >> 4, n16 = lane & 15;
    int blk = blockIdx.x;
    int b = blk / 147, chunk = blk % 147;
    int nb = 98 + chunk*64 + w*16 + n16;

    const short* fb = FBin + (size_t)b*FBST;
    f32x4 acc[5] = {{0,0,0,0},{0,0,0,0},{0,0,0,0},{0,0,0,0},{0,0,0,0}};

    int nbase = nb*128;
    #pragma unroll
    for (int cih = 0; cih < 2; ++cih) {
        bf16x8 bhi = *(const bf16x8*)(fb + nbase + cih*32 + q*8);
        bf16x8 blo = *(const bf16x8*)(fb + nbase + 64 + cih*32 + q*8);
        #pragma unroll
        for (int ct = 0; ct < 5; ++ct) {
            int aoff = (ct*16 + n16)*CHN + cih*32 + q*8;
            bf16x8 ahi = *(const bf16x8*)(Wh + aoff);
            bf16x8 alo = *(const bf16x8*)(Wl + aoff);
            acc[ct] = __builtin_amdgcn_mfma_f32_16x16x32_bf16(ahi, bhi, acc[ct], 0, 0, 0);
            acc[ct] = __builtin_amdgcn_mfma_f32_16x16x32_bf16(ahi, blo, acc[ct], 0, 0, 0);
            acc[ct] = __builtin_amdgcn_mfma_f32_16x16x32_bf16(alo, bhi, acc[ct], 0, 0, 0);
        }
    }

    int yy = nb / PW;
    int xx = nb - yy*PW;
    float kabs[4] = {0.f, 0.f, 0.f, 0.f};
    if (xx >= 1 && xx <= 96 && yy >= 1 && yy <= 96) {
        int n = (yy - 1)*WW + (xx - 1);
        #pragma unroll
        for (int ct = 0; ct < 5; ++ct) {
            #pragma unroll
            for (int r = 0; r < 4; ++r) {
                int co = ct*16 + q*4 + r;
                float v = acc[ct][r];
                if (co < 8)
                    Qb[((size_t)b*NSP + n)*8 + co] = f2b((v + bq[co]) * LOG2E);
                else if (co < 16) {
                    float kv = v + bk[co-8];
                    kabs[r] = fabsf(kv) * 1.01f;
                    Kb[((size_t)b*NSP + n)*8 + (co-8)] = f2b(kv);
                } else
                    Vb[((size_t)(b*CHN + co-16))*NSP + n] = f2b(v + bv[co-16]);
            }
        }
    }
    #pragma unroll
    for (int r = 0; r < 4; ++r) {
        #pragma unroll
        for (int off = 1; off < 16; off <<= 1)
            kabs[r] = fmaxf(kabs[r], __shfl_xor(kabs[r], off));
    }
    if (q >= 2 && n16 == 0) {
        #pragma unroll
        for (int r = 0; r < 4; ++r)
            atomicMax((int*)&Kinf[(q - 2)*4 + r], __float_as_int(kabs[r]));
    }
}

// ---------------------------------------------------------------------------
// chunk buffer for attention double-buffering (compile-time indices only).
struct CB { bf16x8 kf[4]; bf16x8 vf[8]; };

static __device__ __forceinline__ void attn_load(CB& cb,
        const short* __restrict__ Kp, const short* __restrict__ Vp,
        int j0, int quad, int n16, int krow_base) {
    #pragma unroll
    for (int tt = 0; tt < 4; ++tt) {
        bf16x8 z = {0,0,0,0,0,0,0,0};
        cb.kf[tt] = z;
        if (quad == 0) {
            int jrow = j0 + (tt >> 1)*32 + (tt & 1)*4 + krow_base;
            cb.kf[tt] = *(const bf16x8*)(Kp + (size_t)jrow*8);
        }
    }
    #pragma unroll
    for (int ks = 0; ks < 2; ++ks)
        #pragma unroll
        for (int ct = 0; ct < 4; ++ct)
            cb.vf[ks*4 + ct] = *(const bf16x8*)(Vp + (size_t)(ct*16 + n16)*NSP
                                                + j0 + ks*32 + quad*8);
}

static __device__ __forceinline__ void attn_compute(const CB& cb,
        const bf16x8 (&qf)[2], const f32x4 (&ci)[2],
        f32x4 (&accO)[2][4], float (&lp)[2]) {
    f32x4 e[2][4];
    #pragma unroll
    for (int rg = 0; rg < 2; ++rg)
        #pragma unroll
        for (int tt = 0; tt < 4; ++tt)
            e[rg][tt] = __builtin_amdgcn_mfma_f32_16x16x32_bf16(cb.kf[tt], qf[rg], ci[rg], 0, 0, 0);
    #pragma unroll
    for (int rg = 0; rg < 2; ++rg) {
        float s = 0.f;
        #pragma unroll
        for (int tt = 0; tt < 4; ++tt)
            #pragma unroll
            for (int r = 0; r < 4; ++r) {
                float p = __builtin_amdgcn_exp2f(e[rg][tt][r]);
                e[rg][tt][r] = p;
                s += p;
            }
        lp[rg] += s;
    }
    #pragma unroll
    for (int ks = 0; ks < 2; ++ks) {
        #pragma unroll
        for (int rg = 0; rg < 2; ++rg) {
            union { int di[4]; bf16x8 v8; } pu;
            int t2 = ks*2;
            pu.di[0] = __builtin_amdgcn_perm(__float_as_uint(e[rg][t2][1]),
                                             __float_as_uint(e[rg][t2][0]), 0x07060302u);
            pu.di[1] = __builtin_amdgcn_perm(__float_as_uint(e[rg][t2][3]),
                                             __float_as_uint(e[rg][t2][2]), 0x07060302u);
            pu.di[2] = __builtin_amdgcn_perm(__float_as_uint(e[rg][t2+1][1]),
                                             __float_as_uint(e[rg][t2+1][0]), 0x07060302u);
            pu.di[3] = __builtin_amdgcn_perm(__float_as_uint(e[rg][t2+1][3]),
                                             __float_as_uint(e[rg][t2+1][2]), 0x07060302u);
            #pragma unroll
            for (int ct = 0; ct < 4; ++ct)
                accO[rg][ct] = __builtin_amdgcn_mfma_f32_16x16x32_bf16(
                    pu.v8, cb.vf[ks*4 + ct], accO[rg][ct], 0, 0, 0);
        }
    }
}

// MFMA flash attention, bound-based softmax, j-split across 2 blocks,
// register double-buffered K/V prefetch with compile-time buffer selection.
__global__ __launch_bounds__(256) void k_attn_mfma(
        const short* __restrict__ Qb, const short* __restrict__ Kb,
        const short* __restrict__ Vb, const float* __restrict__ Kinf_p,
        float* __restrict__ Opg, float* __restrict__ lg) {
    __shared__ float Opart[4][2][16][68];
    __shared__ float lsh[4][2][16];

    int blk = blockIdx.x;
    int b    = blk / (NRB*2);
    int rb   = (blk % (NRB*2)) >> 1;
    int half = blk & 1;
    int i0 = rb*32;
    int t = threadIdx.x;
    int w = t >> 6;
    int lane = t & 63;
    int quad = lane >> 4, n16 = lane & 15;

    const short* Qp = Qb + ((size_t)b*NSP)*8;
    const short* Kp = Kb + ((size_t)b*NSP)*8;
    const short* Vp = Vb + ((size_t)b*CHN)*NSP;

    bf16x8 qf[2];
    float Mi[2];
    #pragma unroll
    for (int rg = 0; rg < 2; ++rg) {
        bf16x8 z = {0,0,0,0,0,0,0,0};
        qf[rg] = z;
        if (quad == 0)
            qf[rg] = *(const bf16x8*)(Qp + (size_t)(i0 + rg*16 + n16)*8);
        float s1 = 0.f;
        #pragma unroll
        for (int c = 0; c < 8; ++c)
            s1 += fabsf(b2f(qf[rg][c])) * Kinf_p[c];
        float Mv = s1 + 1.0f - BOOST;
        Mi[rg] = __shfl(Mv, n16);
    }

    f32x4 accO[2][4] = {{{0,0,0,0},{0,0,0,0},{0,0,0,0},{0,0,0,0}},
                        {{0,0,0,0},{0,0,0,0},{0,0,0,0},{0,0,0,0}}};
    float lp[2] = {0.f, 0.f};
    f32x4 ci[2];
    #pragma unroll
    for (int rg = 0; rg < 2; ++rg) {
        ci[rg][0] = -Mi[rg]; ci[rg][1] = -Mi[rg];
        ci[rg][2] = -Mi[rg]; ci[rg][3] = -Mi[rg];
    }

    int krow_base = (n16 >> 2)*8 + (n16 & 3);
    int jbase = half*4608 + w*1152;

    CB bufA, bufB;
    attn_load(bufA, Kp, Vp, jbase, quad, n16, krow_base);

    #pragma unroll 1
    for (int jc = 0; jc < 18; jc += 2) {
        attn_load(bufB, Kp, Vp, jbase + (jc + 1)*64, quad, n16, krow_base);
        attn_compute(bufA, qf, ci, accO, lp);
        if (jc + 2 < 18)
            attn_load(bufA, Kp, Vp, jbase + (jc + 2)*64, quad, n16, krow_base);
        attn_compute(bufB, qf, ci, accO, lp);
    }

    #pragma unroll
    for (int rg = 0; rg < 2; ++rg) {
        float l = lp[rg];
        l += __shfl_xor(l, 16);
        l += __shfl_xor(l, 32);
        if (quad == 0) lsh[w][rg][n16] = l;
        #pragma unroll
        for (int ct = 0; ct < 4; ++ct)
            #pragma unroll
            for (int r = 0; r < 4; ++r)
                Opart[w][rg][quad*4 + r][ct*16 + n16] = accO[rg][ct][r];
    }
    __syncthreads();

    int row = t >> 3;            // 0..31
    int rg = row >> 4, ii = row & 15;
    int c0 = (t & 7)*8;
    size_t obase = (((size_t)(b*NRB + rb))*2 + half)*2048 + (size_t)row*64;
    #pragma unroll
    for (int cc = 0; cc < 8; ++cc) {
        int c = c0 + cc;
        Opg[obase + c] = Opart[0][rg][ii][c] + Opart[1][rg][ii][c]
                       + Opart[2][rg][ii][c] + Opart[3][rg][ii][c];
    }
    if ((t & 7) == 0)
        lg[(((size_t)(b*NRB + rb))*2 + half)*32 + row] =
            lsh[0][rg][ii] + lsh[1][rg][ii] + lsh[2][rg][ii] + lsh[3][rg][ii];
}

// ---------------------------------------------------------------------------
// attention finalize: merge 2 j-halves, normalize, add residual, write AT.
__global__ __launch_bounds__(256) void k_attn_fin(
        const float* __restrict__ Opg, const float* __restrict__ lg,
        const float* __restrict__ FR, const float* __restrict__ gamma_p,
        float* __restrict__ AT) {
    int blk = blockIdx.x;            // b*NRB + rb
    int b = blk / NRB, rb = blk % NRB;
    int t = threadIdx.x;
    int row = t >> 3;
    int c0 = (t & 7)*8;
    float g = gamma_p[0];
    size_t ob = ((size_t)blk*2)*2048 + (size_t)row*64;
    float l0 = lg[((size_t)blk*2)*32 + row];
    float l1 = lg[((size_t)blk*2 + 1)*32 + row];
    float inv = g / fmaxf(l0 + l1, 1e-35f);
    int gi = rb*32 + row;
    int iy = gi / WW, ix = gi - iy*WW;
    size_t frb = ((size_t)b*PN + (iy + 1)*PW + ix + 1)*CHN;
    size_t atb = ((size_t)b*PN2 + (iy + 4)*PW2 + ix + 4)*CHN;
    #pragma unroll
    for (int cc = 0; cc < 8; ++cc) {
        int c = c0 + cc;
        float Ov = Opg[ob + c] + Opg[ob + 2048 + c];
        AT[atb + c] = Ov*inv + FR[frb + c];
    }
}

// ---------------------------------------------------------------------------
// conv 9x9 (64 -> 3) + tanh. Wave per 4 pixels, lane = ci.
__global__ __launch_bounds__(256) void k_conv_out(const float* __restrict__ AT,
        const float* __restrict__ Wo, const float* __restrict__ bias,
        float* __restrict__ out) {
    int t = threadIdx.x;
    int w = t >> 6, lane = t & 63;
    int base = blockIdx.x*16 + w*4;
    int b = base / NSP;
    int n0 = base % NSP;
    int y0 = n0 / WW, x0 = n0 % WW;

    float s[4][3] = {{0,0,0},{0,0,0},{0,0,0},{0,0,0}};
    for (int ky = 0; ky < 9; ++ky) {
        const float* arow = AT + ((size_t)b*PN2 + (size_t)(y0 + ky)*PW2 + x0)*CHN + lane;
        const float* wrow = Wo + (size_t)ky*9*192;
        float xv[12];
        #pragma unroll
        for (int u = 0; u < 12; ++u)
            xv[u] = arow[(size_t)u*CHN];
        #pragma unroll
        for (int kx = 0; kx < 9; ++kx) {
            float w0 = wrow[kx*192 +   0 + lane];
            float w1 = wrow[kx*192 +  64 + lane];
            float w2 = wrow[kx*192 + 128 + lane];
            #pragma unroll
            for (int p = 0; p < 4; ++p) {
                float x = xv[kx + p];
                s[p][0] = fmaf(x, w0, s[p][0]);
                s[p][1] = fmaf(x, w1, s[p][1]);
                s[p][2] = fmaf(x, w2, s[p][2]);
            }
        }
    }
    #pragma unroll
    for (int p = 0; p < 4; ++p)
        #pragma unroll
        for (int c = 0; c < 3; ++c) {
            float v = s[p][c];
            v += __shfl_xor(v, 1);
            v += __shfl_xor(v, 2);
            v += __shfl_xor(v, 4);
            v += __shfl_xor(v, 8);
            v += __shfl_xor(v, 16);
            v += __shfl_xor(v, 32);
            s[p][c] = v;
        }
    #pragma unroll
    for (int p = 0; p < 4; ++p)
        #pragma unroll
        for (int c = 0; c < 3; ++c)
            if (lane == p*3 + c)
                out[((size_t)(b*3 + c))*NSP + n0 + p] = tanhf(s[p][c] + bias[c]);
}

// ---------------------------------------------------------------------------
extern "C" void kernel_launch(void* const* d_in, const int* in_sizes, int n_in,
                              void* d_out, int out_size, void* d_ws, size_t ws_size,
                              hipStream_t stream) {
    (void)in_sizes; (void)n_in; (void)out_size; (void)ws_size;
    const float* x     = (const float*)d_in[0];
    const float* w_in  = (const float*)d_in[1];
    const float* b_in  = (const float*)d_in[2];
    const float* a_in  = (const float*)d_in[3];
    const float* rw1   = (const float*)d_in[4];
    const float* rb1   = (const float*)d_in[5];
    const float* ra    = (const float*)d_in[6];
    const float* rw2   = (const float*)d_in[7];
    const float* rb2   = (const float*)d_in[8];
    const float* wq    = (const float*)d_in[9];
    const float* bq    = (const float*)d_in[10];
    const float* wk    = (const float*)d_in[11];
    const float* bk    = (const float*)d_in[12];
    const float* wv    = (const float*)d_in[13];
    const float* bv    = (const float*)d_in[14];
    const float* gamma = (const float*)d_in[15];
    const float* w_out = (const float*)d_in[16];
    const float* b_out = (const float*)d_in[17];

    const size_t SZ_FR  = (size_t)BATCH*PN*CHN*4;        // 4,917,248
    const size_t SZ_FBI = (size_t)BATCH*FBST*2;          // 5,048,320
    const size_t SZ_WT  = (size_t)NBLK*2*9*CHN*CHN*2;    //   737,280
    const size_t SZ_QK  = (size_t)BATCH*NSP*C8*2;        //   294,912
    const size_t SZ_VB  = (size_t)BATCH*CHN*NSP*2;       // 2,359,296
    const size_t SZ_AT  = (size_t)BATCH*PN2*CHN*4;       // 5,537,792
    const size_t SZ_WO  = (size_t)81*CIN*CHN*4;          //    62,208
    const size_t SZ_WIN = (size_t)243*CHN*4;             //    62,208
    const size_t SZ_WQ  = (size_t)80*CHN*2;              //    10,240
    const size_t SZ_OP  = (size_t)BATCH*NRB*2*32*64*4;   // 18,874,368
    const size_t SZ_LG  = (size_t)BATCH*NRB*2*32*4;      //   147,456
    char* p = (char*)d_ws;
    float* FR      = (float*)p;           p += SZ_FR;
    short* FBI0raw = (short*)p;           p += SZ_FBI;
    short* FBI1raw = (short*)p;           p += SZ_FBI;
    short* Whi     = (short*)p;           p += SZ_WT;
    short* Wlo     = (short*)p;           p += SZ_WT;
    short* Qb16    = (short*)p;           p += SZ_QK;
    short* Kb16    = (short*)p;           p += SZ_QK;
    short* Vb16    = (short*)p;           p += SZ_VB;
    float* AT      = (float*)p;           p += SZ_AT;
    float* Wo      = (float*)p;           p += SZ_WO;
    float* Win     = (float*)p;           p += SZ_WIN;
    short* Wqh     = (short*)p;           p += SZ_WQ;
    short* Wql     = (short*)p;           p += SZ_WQ;
    float* Opg     = (float*)p;           p += SZ_OP;
    float* lgb     = (float*)p;           p += SZ_LG;
    float* Kinf    = (float*)p;           p += 32;
    short* FBI0 = FBI0raw + (size_t)GUARD*128;
    short* FBI1 = FBI1raw + (size_t)GUARD*128;
    float* outp = (float*)d_out;

    hipMemsetAsync(FR, 0, SZ_FR, stream);
    hipMemsetAsync(FBI0raw, 0, SZ_FBI, stream);
    hipMemsetAsync(FBI1raw, 0, SZ_FBI, stream);
    hipMemsetAsync(AT, 0, SZ_AT, stream);
    hipMemsetAsync(Kinf, 0, 32, stream);

    dim3 blk(256);

    k_prep_w<<<(NBLK*2*9*CHN*CHN + 255)/256, blk, 0, stream>>>(rw1, rw2, Whi, Wlo);
    k_prep_wqkv<<<(80*CHN + 255)/256, blk, 0, stream>>>(wq, wk, wv, Wqh, Wql);
    k_prep_wout<<<(81*CIN*CHN + 255)/256, blk, 0, stream>>>(w_out, Wo);
    k_prep_win<<<(243*CHN + 255)/256, blk, 0, stream>>>(w_in, Win);
    k_conv_in<<<BATCH*96*3, blk, 0, stream>>>(x, Win, b_in, a_in, FR, FBI0);
    for (int i = 0; i < NBLK; ++i) {
        k_conv3_mfma<<<BATCH*576, blk, 0, stream>>>(
            FBI0,
            Whi + (size_t)(2*i)*9*CHN*CHN, Wlo + (size_t)(2*i)*9*CHN*CHN,
            rb1 + i*CHN, ra + i, (float*)nullptr, FBI1, 0);
        k_conv3_mfma<<<BATCH*576, blk, 0, stream>>>(
            FBI1,
            Whi + (size_t)(2*i+1)*9*CHN*CHN, Wlo + (size_t)(2*i+1)*9*CHN*CHN,
            rb2 + i*CHN, ra + i, FR, FBI0, 1);
    }
    k_qkv_mfma<<<BATCH*147, blk, 0, stream>>>(
        FBI0, Wqh, Wql, bq, bk, bv, Qb16, Kb16, Vb16, Kinf);
    k_attn_mfma<<<BATCH*NRB*2, blk, 0, stream>>>(
        Qb16, Kb16, Vb16, Kinf, Opg, lgb);
    k_attn_fin<<<BATCH*NRB, blk, 0, stream>>>(Opg, lgb, FR, gamma, AT);
    k_conv_out<<<(BATCH*NSP)/16, blk, 0, stream>>>(AT, Wo, b_out, outp);
}